// Round 1
// baseline (549.554 us; speedup 1.0000x reference)
//
#include <hip/hip_runtime.h>
#include <cmath>

// ---------------------------------------------------------------- types
typedef __bf16 bf16x8 __attribute__((ext_vector_type(8)));
typedef float  floatx4 __attribute__((ext_vector_type(4)));

#define LN_EPS 1e-5f
#define COS_EPS 1e-8f
#define TEMP 8.0f   // sqrt(64)

// B=32 S=512 D=512 H=8 DK=DV=64 DFF=2048, M = B*S = 16384
static const int Mrows = 16384;

__device__ __forceinline__ void gload_lds16(const void* g, void* l) {
  __builtin_amdgcn_global_load_lds(
      (const __attribute__((address_space(1))) void*)g,
      (__attribute__((address_space(3))) void*)l, 16, 0, 0);
}

// ---------------------------------------------------------------- prep kernels
__global__ __launch_bounds__(256) void convert_bf16(const float* __restrict__ src,
                                                    __bf16* __restrict__ dst, int n4) {
  int i = blockIdx.x * 256 + threadIdx.x;
  if (i < n4) {
    float4 v = ((const float4*)src)[i];
    dst[i * 4 + 0] = (__bf16)v.x;
    dst[i * 4 + 1] = (__bf16)v.y;
    dst[i * 4 + 2] = (__bf16)v.z;
    dst[i * 4 + 3] = (__bf16)v.w;
  }
}

// dst[c*R + r] = src[r*C + c]  (src fp32 [R,C] -> dst bf16 [C,R])
__global__ __launch_bounds__(256) void transpose_to_bf16(const float* __restrict__ src,
                                                         __bf16* __restrict__ dst,
                                                         int R, int C) {
  int idx = blockIdx.x * 256 + threadIdx.x;
  if (idx < R * C) {
    int r = idx / C, c = idx % C;
    dst[(size_t)c * R + r] = (__bf16)src[idx];
  }
}

// ---------------------------------------------------------------- GEMM  C = A[M,K] * Bt[N,K]^T
// EPI: 0 -> bf16 out, 1 -> f32 out, 2 -> +bias,relu -> bf16, 3 -> +bias -> f32
template <int EPI>
__global__ __launch_bounds__(256) void gemm_bt(const __bf16* __restrict__ A,
                                               const __bf16* __restrict__ Bt,
                                               void* __restrict__ Cv,
                                               const float* __restrict__ bias,
                                               int Ndim, int Kdim) {
  __shared__ __bf16 As[128 * 32];
  __shared__ __bf16 Bs[128 * 32];
  const int tid = threadIdx.x;
  const int wave = tid >> 6, lane = tid & 63;
  const int l15 = lane & 15, quad = lane >> 4;
  const int m0 = blockIdx.y * 128, n0 = blockIdx.x * 128;
  const int wrow = (wave >> 1) * 64, wcol = (wave & 1) * 64;

  floatx4 zero = {0.f, 0.f, 0.f, 0.f};
  floatx4 acc[4][4];
  for (int i = 0; i < 4; ++i)
    for (int j = 0; j < 4; ++j) acc[i][j] = zero;

  for (int kt = 0; kt < Kdim; kt += 32) {
    __syncthreads();
    // stage 16 KB: 16 chunks of 1 KB (16 rows x 64B); wave w takes chunks w*4..w*4+3
    for (int c = 0; c < 4; ++c) {
      int g = wave * 4 + c;
      const __bf16* src;
      __bf16* dst;
      if (g < 8) {
        int row = m0 + g * 16 + (lane >> 2);
        src = A + (size_t)row * Kdim + kt + (lane & 3) * 8;
        dst = As + g * 512;
      } else {
        int g2 = g - 8;
        int row = n0 + g2 * 16 + (lane >> 2);
        src = Bt + (size_t)row * Kdim + kt + (lane & 3) * 8;
        dst = Bs + g2 * 512;
      }
      gload_lds16(src, dst + lane * 8);
    }
    __syncthreads();
    bf16x8 a[4], b[4];
    for (int i = 0; i < 4; ++i)
      a[i] = *(const bf16x8*)(As + (wrow + i * 16 + l15) * 32 + quad * 8);
    for (int j = 0; j < 4; ++j)
      b[j] = *(const bf16x8*)(Bs + (wcol + j * 16 + l15) * 32 + quad * 8);
    for (int i = 0; i < 4; ++i)
      for (int j = 0; j < 4; ++j)
        acc[i][j] = __builtin_amdgcn_mfma_f32_16x16x32_bf16(a[i], b[j], acc[i][j], 0, 0, 0);
  }

  for (int i = 0; i < 4; ++i)
    for (int j = 0; j < 4; ++j) {
      int row = m0 + wrow + i * 16 + quad * 4;
      int col = n0 + wcol + j * 16 + l15;
      float bv = (EPI >= 2) ? bias[col] : 0.f;
      for (int r = 0; r < 4; ++r) {
        float v = acc[i][j][r];
        size_t idx = (size_t)(row + r) * Ndim + col;
        if (EPI == 0) {
          ((__bf16*)Cv)[idx] = (__bf16)v;
        } else if (EPI == 1) {
          ((float*)Cv)[idx] = v;
        } else if (EPI == 2) {
          v += bv;
          v = v > 0.f ? v : 0.f;
          ((__bf16*)Cv)[idx] = (__bf16)v;
        } else {
          ((float*)Cv)[idx] = v + bv;
        }
      }
    }
}

// ---------------------------------------------------------------- q/k norms
// norms layout: [0,131072) = ||q|| at bh*512+s ; [131072,262144) = ||k||
__global__ __launch_bounds__(256) void norms_kernel(const __bf16* __restrict__ qkv,
                                                    float* __restrict__ norms) {
  int gid = blockIdx.x * 256 + threadIdx.x;
  int row = gid >> 4, l = gid & 15;
  if (row >= 262144) return;
  int kind = row >> 17;          // 0=q, 1=k
  int r = row & 131071;
  int bh = r >> 9, s = r & 511;
  int b = bh >> 3, h = bh & 7;
  const __bf16* p = qkv + (size_t)(b * 512 + s) * 1536 + kind * 512 + h * 64 + l * 4;
  float sum = 0.f;
  for (int t = 0; t < 4; ++t) {
    float v = (float)p[t];
    sum += v * v;
  }
  for (int m = 1; m < 16; m <<= 1) sum += __shfl_xor(sum, m, 64);
  if (l == 0) norms[row] = sqrtf(sum);
}

// ---------------------------------------------------------------- flash attention per (b,h,qtile)
__global__ __launch_bounds__(256) void attn_kernel(const __bf16* __restrict__ qkv,
                                                   const float* __restrict__ norms,
                                                   __bf16* __restrict__ out) {
  __shared__ __bf16 Vt[64 * 64];       // [d][sk]
  __shared__ __bf16 P[4][16 * 64];     // per wave [q][sk]
  const int tid = threadIdx.x, wave = tid >> 6, lane = tid & 63;
  const int l15 = lane & 15, quad = lane >> 4;
  const int qt = blockIdx.x;           // 0..7
  const int bh = blockIdx.y;           // 0..255
  const int b = bh >> 3, h = bh & 7;
  const __bf16* Qb = qkv + (size_t)(b * 512) * 1536 + h * 64;
  const __bf16* Kb = Qb + 512;
  const __bf16* Vb = Qb + 1024;
  const int wq0 = qt * 64 + wave * 16;

  bf16x8 aq[2];
  {
    int qrow = wq0 + l15;
    aq[0] = *(const bf16x8*)(Qb + (size_t)qrow * 1536 + quad * 8);
    aq[1] = *(const bf16x8*)(Qb + (size_t)qrow * 1536 + 32 + quad * 8);
  }
  float nq_r[4];
  for (int r = 0; r < 4; ++r) nq_r[r] = norms[bh * 512 + wq0 + quad * 4 + r];
  const float* nkbase = norms + 131072 + bh * 512;

  floatx4 zero = {0.f, 0.f, 0.f, 0.f};
  floatx4 o[4];
  float m_i[4], l_i[4];
  for (int r = 0; r < 4; ++r) {
    m_i[r] = -1e30f;
    l_i[r] = 0.f;
  }
  for (int jd = 0; jd < 4; ++jd) o[jd] = zero;

  for (int t = 0; t < 8; ++t) {
    int sk0 = t * 64;
    __syncthreads();
    // stage V tile transposed: Vt[d][sk]
    for (int i = 0; i < 16; ++i) {
      int idx = tid + i * 256;
      int sk = idx >> 6, d = idx & 63;
      Vt[d * 64 + sk] = Vb[(size_t)(sk0 + sk) * 1536 + d];
    }
    __syncthreads();
    // scores: 16q x 64k per wave
    floatx4 c[4];
    for (int j = 0; j < 4; ++j) {
      bf16x8 bk0 = *(const bf16x8*)(Kb + (size_t)(sk0 + j * 16 + l15) * 1536 + quad * 8);
      bf16x8 bk1 = *(const bf16x8*)(Kb + (size_t)(sk0 + j * 16 + l15) * 1536 + 32 + quad * 8);
      floatx4 z = zero;
      z = __builtin_amdgcn_mfma_f32_16x16x32_bf16(aq[0], bk0, z, 0, 0, 0);
      z = __builtin_amdgcn_mfma_f32_16x16x32_bf16(aq[1], bk1, z, 0, 0, 0);
      c[j] = z;
    }
    float nk_c[4];
    for (int j = 0; j < 4; ++j) nk_c[j] = nkbase[sk0 + j * 16 + l15];
    float sv[4][4], tm[4];
    for (int r = 0; r < 4; ++r) tm[r] = -1e30f;
    for (int j = 0; j < 4; ++j)
      for (int r = 0; r < 4; ++r) {
        float den = nq_r[r] * nk_c[j];
        den = den > COS_EPS ? den : COS_EPS;
        float v = c[j][r] / (den * TEMP);
        sv[j][r] = v;
        tm[r] = fmaxf(tm[r], v);
      }
    for (int m = 1; m < 16; m <<= 1)
      for (int r = 0; r < 4; ++r) tm[r] = fmaxf(tm[r], __shfl_xor(tm[r], m, 64));
    float alpha[4];
    for (int r = 0; r < 4; ++r) {
      float mnew = fmaxf(m_i[r], tm[r]);
      alpha[r] = __expf(m_i[r] - mnew);
      m_i[r] = mnew;
    }
    float ts[4] = {0.f, 0.f, 0.f, 0.f};
    for (int j = 0; j < 4; ++j)
      for (int r = 0; r < 4; ++r) {
        float p = __expf(sv[j][r] - m_i[r]);
        sv[j][r] = p;
        ts[r] += p;
      }
    for (int m = 1; m < 16; m <<= 1)
      for (int r = 0; r < 4; ++r) ts[r] += __shfl_xor(ts[r], m, 64);
    for (int r = 0; r < 4; ++r) l_i[r] = l_i[r] * alpha[r] + ts[r];
    for (int jd = 0; jd < 4; ++jd)
      for (int r = 0; r < 4; ++r) o[jd][r] *= alpha[r];
    // P -> LDS (C-layout write), re-read in A-layout
    for (int j = 0; j < 4; ++j)
      for (int r = 0; r < 4; ++r)
        P[wave][(quad * 4 + r) * 64 + j * 16 + l15] = (__bf16)sv[j][r];
    __syncthreads();
    for (int kk = 0; kk < 2; ++kk) {
      bf16x8 ap = *(const bf16x8*)(&P[wave][l15 * 64 + kk * 32 + quad * 8]);
      for (int jd = 0; jd < 4; ++jd) {
        bf16x8 bv = *(const bf16x8*)(&Vt[(jd * 16 + l15) * 64 + kk * 32 + quad * 8]);
        o[jd] = __builtin_amdgcn_mfma_f32_16x16x32_bf16(ap, bv, o[jd], 0, 0, 0);
      }
    }
  }
  for (int jd = 0; jd < 4; ++jd)
    for (int r = 0; r < 4; ++r) {
      int q = wq0 + quad * 4 + r;
      int d = jd * 16 + l15;
      out[(size_t)(b * 512 + q) * 512 + h * 64 + d] = (__bf16)(o[jd][r] / l_i[r]);
    }
}

// ---------------------------------------------------------------- residual + layernorm
template <bool WB>
__global__ __launch_bounds__(256) void resid_ln(const float* __restrict__ X1,
                                                const float* __restrict__ X2,
                                                const float* __restrict__ g,
                                                const float* __restrict__ be,
                                                float* __restrict__ outf,
                                                __bf16* __restrict__ outb) {
  int row = blockIdx.x * 4 + (threadIdx.x >> 6);
  int lane = threadIdx.x & 63;
  const float4* r1 = (const float4*)(X1 + (size_t)row * 512);
  const float4* r2 = (const float4*)(X2 + (size_t)row * 512);
  float4 a = r1[lane], b = r2[lane];
  float4 cc = r1[lane + 64], d = r2[lane + 64];
  float v[8] = {a.x + b.x, a.y + b.y, a.z + b.z, a.w + b.w,
                cc.x + d.x, cc.y + d.y, cc.z + d.z, cc.w + d.w};
  float s = 0.f, sq = 0.f;
  for (int i = 0; i < 8; ++i) {
    s += v[i];
    sq += v[i] * v[i];
  }
  for (int m = 1; m < 64; m <<= 1) {
    s += __shfl_xor(s, m, 64);
    sq += __shfl_xor(sq, m, 64);
  }
  float mean = s * (1.f / 512.f);
  float var = sq * (1.f / 512.f) - mean * mean;
  float rstd = rsqrtf(var + LN_EPS);
  float4 g0 = ((const float4*)g)[lane], g1 = ((const float4*)g)[lane + 64];
  float4 b0 = ((const float4*)be)[lane], b1 = ((const float4*)be)[lane + 64];
  float gg[8] = {g0.x, g0.y, g0.z, g0.w, g1.x, g1.y, g1.z, g1.w};
  float bb[8] = {b0.x, b0.y, b0.z, b0.w, b1.x, b1.y, b1.z, b1.w};
  float o[8];
  for (int i = 0; i < 8; ++i) o[i] = (v[i] - mean) * rstd * gg[i] + bb[i];
  float4 w0 = {o[0], o[1], o[2], o[3]}, w1 = {o[4], o[5], o[6], o[7]};
  ((float4*)(outf + (size_t)row * 512))[lane] = w0;
  ((float4*)(outf + (size_t)row * 512))[lane + 64] = w1;
  if (WB) {
    __bf16* ob = outb + (size_t)row * 512;
    for (int i = 0; i < 4; ++i) ob[lane * 4 + i] = (__bf16)o[i];
    for (int i = 0; i < 4; ++i) ob[256 + lane * 4 + i] = (__bf16)o[4 + i];
  }
}

// ---------------------------------------------------------------- launcher
extern "C" void kernel_launch(void* const* d_in, const int* in_sizes, int n_in,
                              void* d_out, int out_size, void* d_ws, size_t ws_size,
                              hipStream_t stream) {
  const float* x     = (const float*)d_in[0];
  const float* w_q   = (const float*)d_in[1];
  const float* w_k   = (const float*)d_in[2];
  const float* w_v   = (const float*)d_in[3];
  const float* w_o   = (const float*)d_in[4];
  const float* w_ff1 = (const float*)d_in[5];
  const float* b_ff1 = (const float*)d_in[6];
  const float* w_ff2 = (const float*)d_in[7];
  const float* b_ff2 = (const float*)d_in[8];
  const float* g1    = (const float*)d_in[9];
  const float* b1    = (const float*)d_in[10];
  const float* g2    = (const float*)d_in[11];
  const float* b2    = (const float*)d_in[12];
  float* out = (float*)d_out;

  char* ws = (char*)d_ws;
  size_t off = 0;
  auto alloc = [&](size_t bytes) -> void* {
    void* p = ws + off;
    off += (bytes + 255) & ~(size_t)255;
    return p;
  };
  __bf16* xb     = (__bf16*)alloc((size_t)Mrows * 512 * 2);
  __bf16* wt_qkv = (__bf16*)alloc((size_t)1536 * 512 * 2);
  __bf16* wt_o   = (__bf16*)alloc((size_t)512 * 512 * 2);
  __bf16* wt_ff1 = (__bf16*)alloc((size_t)2048 * 512 * 2);
  __bf16* wt_ff2 = (__bf16*)alloc((size_t)512 * 2048 * 2);
  __bf16* qkv    = (__bf16*)alloc((size_t)Mrows * 1536 * 2);
  float*  norms  = (float*)alloc((size_t)262144 * 4);
  __bf16* attn   = (__bf16*)alloc((size_t)Mrows * 512 * 2);
  float*  proj   = (float*)alloc((size_t)Mrows * 512 * 4);   // reused as ffn out
  float*  h1f    = (float*)alloc((size_t)Mrows * 512 * 4);
  __bf16* h1b    = (__bf16*)alloc((size_t)Mrows * 512 * 2);
  __bf16* mid    = (__bf16*)alloc((size_t)Mrows * 2048 * 2);

  convert_bf16<<<8192, 256, 0, stream>>>(x, xb, Mrows * 512 / 4);
  transpose_to_bf16<<<1024, 256, 0, stream>>>(w_q, wt_qkv, 512, 512);
  transpose_to_bf16<<<1024, 256, 0, stream>>>(w_k, wt_qkv + 512 * 512, 512, 512);
  transpose_to_bf16<<<1024, 256, 0, stream>>>(w_v, wt_qkv + 2 * 512 * 512, 512, 512);
  transpose_to_bf16<<<1024, 256, 0, stream>>>(w_o, wt_o, 512, 512);
  transpose_to_bf16<<<4096, 256, 0, stream>>>(w_ff1, wt_ff1, 512, 2048);
  transpose_to_bf16<<<4096, 256, 0, stream>>>(w_ff2, wt_ff2, 2048, 512);

  gemm_bt<0><<<dim3(12, 128), 256, 0, stream>>>(xb, wt_qkv, qkv, nullptr, 1536, 512);
  norms_kernel<<<16384, 256, 0, stream>>>(qkv, norms);
  attn_kernel<<<dim3(8, 256), 256, 0, stream>>>(qkv, norms, attn);
  gemm_bt<1><<<dim3(4, 128), 256, 0, stream>>>(attn, wt_o, proj, nullptr, 512, 512);
  resid_ln<true><<<4096, 256, 0, stream>>>(x, proj, g1, b1, h1f, h1b);
  gemm_bt<2><<<dim3(16, 128), 256, 0, stream>>>(h1b, wt_ff1, mid, b_ff1, 2048, 512);
  gemm_bt<3><<<dim3(4, 128), 256, 0, stream>>>(mid, wt_ff2, proj, b_ff2, 512, 2048);
  resid_ln<false><<<4096, 256, 0, stream>>>(h1f, proj, g2, b2, out, nullptr);
}

// Round 2
// 413.916 us; speedup vs baseline: 1.3277x; 1.3277x over previous
//
#include <hip/hip_runtime.h>
#include <cmath>

// ---------------------------------------------------------------- types
typedef __bf16 bf16x8 __attribute__((ext_vector_type(8)));
typedef float  floatx4 __attribute__((ext_vector_type(4)));

#define LN_EPS 1e-5f
#define COS_EPS 1e-8f
#define INV_TEMP 0.125f   // 1/sqrt(64)

// B=32 S=512 D=512 H=8 DK=DV=64 DFF=2048, M = B*S = 16384
static const int Mrows = 16384;

__device__ __forceinline__ void gload_lds16(const void* g, void* l) {
  __builtin_amdgcn_global_load_lds(
      (const __attribute__((address_space(1))) void*)g,
      (__attribute__((address_space(3))) void*)l, 16, 0, 0);
}

// ---------------------------------------------------------------- prep kernels
__global__ __launch_bounds__(256) void convert_bf16(const float* __restrict__ src,
                                                    __bf16* __restrict__ dst, int n4) {
  int i = blockIdx.x * 256 + threadIdx.x;
  if (i < n4) {
    float4 v = ((const float4*)src)[i];
    dst[i * 4 + 0] = (__bf16)v.x;
    dst[i * 4 + 1] = (__bf16)v.y;
    dst[i * 4 + 2] = (__bf16)v.z;
    dst[i * 4 + 3] = (__bf16)v.w;
  }
}

// dst[c*R + r] = src[r*C + c]  (src fp32 [R,C] -> dst bf16 [C,R])
__global__ __launch_bounds__(256) void transpose_to_bf16(const float* __restrict__ src,
                                                         __bf16* __restrict__ dst,
                                                         int R, int C) {
  int idx = blockIdx.x * 256 + threadIdx.x;
  if (idx < R * C) {
    int r = idx / C, c = idx % C;
    dst[(size_t)c * R + r] = (__bf16)src[idx];
  }
}

// ---------------------------------------------------------------- GEMM  C = A[M,K] * Bt[N,K]^T
// EPI: 0 -> bf16 out, 1 -> f32 out, 2 -> +bias,relu -> bf16, 3 -> +bias -> f32
template <int EPI>
__global__ __launch_bounds__(256) void gemm_bt(const __bf16* __restrict__ A,
                                               const __bf16* __restrict__ Bt,
                                               void* __restrict__ Cv,
                                               const float* __restrict__ bias,
                                               int Ndim, int Kdim) {
  __shared__ __align__(16) __bf16 As[128 * 32];
  __shared__ __align__(16) __bf16 Bs[128 * 32];
  const int tid = threadIdx.x;
  const int wave = tid >> 6, lane = tid & 63;
  const int l15 = lane & 15, quad = lane >> 4;
  const int m0 = blockIdx.y * 128, n0 = blockIdx.x * 128;
  const int wrow = (wave >> 1) * 64, wcol = (wave & 1) * 64;

  floatx4 zero = {0.f, 0.f, 0.f, 0.f};
  floatx4 acc[4][4];
  for (int i = 0; i < 4; ++i)
    for (int j = 0; j < 4; ++j) acc[i][j] = zero;

  for (int kt = 0; kt < Kdim; kt += 32) {
    __syncthreads();
    for (int c = 0; c < 4; ++c) {
      int g = wave * 4 + c;
      const __bf16* src;
      __bf16* dst;
      if (g < 8) {
        int row = m0 + g * 16 + (lane >> 2);
        src = A + (size_t)row * Kdim + kt + (lane & 3) * 8;
        dst = As + g * 512;
      } else {
        int g2 = g - 8;
        int row = n0 + g2 * 16 + (lane >> 2);
        src = Bt + (size_t)row * Kdim + kt + (lane & 3) * 8;
        dst = Bs + g2 * 512;
      }
      gload_lds16(src, dst + lane * 8);
    }
    __syncthreads();
    bf16x8 a[4], b[4];
    for (int i = 0; i < 4; ++i)
      a[i] = *(const bf16x8*)(As + (wrow + i * 16 + l15) * 32 + quad * 8);
    for (int j = 0; j < 4; ++j)
      b[j] = *(const bf16x8*)(Bs + (wcol + j * 16 + l15) * 32 + quad * 8);
    for (int i = 0; i < 4; ++i)
      for (int j = 0; j < 4; ++j)
        acc[i][j] = __builtin_amdgcn_mfma_f32_16x16x32_bf16(a[i], b[j], acc[i][j], 0, 0, 0);
  }

  for (int i = 0; i < 4; ++i)
    for (int j = 0; j < 4; ++j) {
      int row = m0 + wrow + i * 16 + quad * 4;
      int col = n0 + wcol + j * 16 + l15;
      float bv = (EPI >= 2) ? bias[col] : 0.f;
      for (int r = 0; r < 4; ++r) {
        float v = acc[i][j][r];
        size_t idx = (size_t)(row + r) * Ndim + col;
        if (EPI == 0) {
          ((__bf16*)Cv)[idx] = (__bf16)v;
        } else if (EPI == 1) {
          ((float*)Cv)[idx] = v;
        } else if (EPI == 2) {
          v += bv;
          v = v > 0.f ? v : 0.f;
          ((__bf16*)Cv)[idx] = (__bf16)v;
        } else {
          ((float*)Cv)[idx] = v + bv;
        }
      }
    }
}

// ---------------------------------------------------------------- q/k norms
// norms layout: [0,131072) = ||q|| at bh*512+s ; [131072,262144) = ||k||
__global__ __launch_bounds__(256) void norms_kernel(const __bf16* __restrict__ qkv,
                                                    float* __restrict__ norms) {
  int gid = blockIdx.x * 256 + threadIdx.x;
  int row = gid >> 4, l = gid & 15;
  if (row >= 262144) return;
  int kind = row >> 17;          // 0=q, 1=k
  int r = row & 131071;
  int bh = r >> 9, s = r & 511;
  int b = bh >> 3, h = bh & 7;
  const __bf16* p = qkv + (size_t)(b * 512 + s) * 1536 + kind * 512 + h * 64 + l * 4;
  float sum = 0.f;
  for (int t = 0; t < 4; ++t) {
    float v = (float)p[t];
    sum += v * v;
  }
  for (int m = 1; m < 16; m <<= 1) sum += __shfl_xor(sum, m, 64);
  if (l == 0) norms[row] = sqrtf(sum);
}

// ---------------------------------------------------------------- V transpose: qkv v-part -> Vt_g[bh][64][512]
__global__ __launch_bounds__(256) void vtrans_kernel(const __bf16* __restrict__ qkv,
                                                     __bf16* __restrict__ vtg) {
  __shared__ __align__(16) unsigned short til[64][68];  // +4 pad -> 136B row stride
  const int tid = threadIdx.x;
  const int st = blockIdx.x;        // s-tile 0..7
  const int bh = blockIdx.y;        // 0..255
  const int b = bh >> 3, h = bh & 7;
  const unsigned short* src = (const unsigned short*)qkv +
      (size_t)(b * 512 + st * 64) * 1536 + 1024 + h * 64;
  // read tile [64 s][64 d] coalesced
  for (int it = 0; it < 2; ++it) {
    int row = it * 32 + (tid >> 3);
    int c8 = (tid & 7) * 8;
    bf16x8 v = *(const bf16x8*)((const __bf16*)src + (size_t)row * 1536 + c8);
    for (int i = 0; i < 8; ++i) til[row][c8 + i] = ((unsigned short*)&v)[i];
  }
  __syncthreads();
  // write transposed rows [d][s] coalesced
  unsigned short* dst = (unsigned short*)vtg + (size_t)bh * 32768 + st * 64;
  for (int it = 0; it < 2; ++it) {
    int d = it * 32 + (tid >> 3);
    int s8 = (tid & 7) * 8;
    unsigned short v[8];
    for (int i = 0; i < 8; ++i) v[i] = til[s8 + i][d];
    *(bf16x8*)(dst + (size_t)d * 512 + s8) = *(bf16x8*)v;
  }
}

// ---------------------------------------------------------------- attention: block = (qhalf, bh), K/V staged per 64-k tile
__global__ __launch_bounds__(256) void attn_kernel(const __bf16* __restrict__ qkv,
                                                   const __bf16* __restrict__ vtg,
                                                   const float* __restrict__ norms,
                                                   __bf16* __restrict__ out) {
  __shared__ __align__(16) __bf16 Ks[2][64 * 32];   // [kk(d-half)][sk][32 d]
  __shared__ __align__(16) __bf16 Vs[2][64 * 32];   // [kk(sk-half)][d][32 sk]
  __shared__ __align__(16) __bf16 P[4][16 * 72];    // per-wave [q][64 sk +8 pad]
  const int tid = threadIdx.x, wave = tid >> 6, lane = tid & 63;
  const int l15 = lane & 15, quad = lane >> 4;
  const int qh = blockIdx.x;        // 0..1
  const int bh = blockIdx.y;        // 0..255
  const int b = bh >> 3, h = bh & 7;
  const int qbase = qh * 256 + wave * 64;

  const __bf16* Qb = qkv + (size_t)(b * 512) * 1536 + h * 64;
  const __bf16* Kb = Qb + 512;
  const __bf16* Vtb = vtg + (size_t)bh * 32768;
  const float* nkbase = norms + 131072 + bh * 512;
  __bf16* Pw = P[wave];

  // preload Q fragments + q norms (fixed rows for the whole kernel)
  bf16x8 aq[4][2];
  float nq[4][4];
  for (int ch = 0; ch < 4; ++ch) {
    int qrow = qbase + ch * 16;
    aq[ch][0] = *(const bf16x8*)(Qb + (size_t)(qrow + l15) * 1536 + quad * 8);
    aq[ch][1] = *(const bf16x8*)(Qb + (size_t)(qrow + l15) * 1536 + 32 + quad * 8);
    for (int r = 0; r < 4; ++r) nq[ch][r] = norms[bh * 512 + qrow + quad * 4 + r];
  }

  floatx4 zero = {0.f, 0.f, 0.f, 0.f};
  floatx4 o[4][4];
  float lsum[4][4];
  for (int ch = 0; ch < 4; ++ch)
    for (int jd = 0; jd < 4; ++jd) o[ch][jd] = zero;
  for (int ch = 0; ch < 4; ++ch)
    for (int r = 0; r < 4; ++r) lsum[ch][r] = 0.f;

  for (int kt = 0; kt < 8; ++kt) {
    int s0 = kt * 64;
    __syncthreads();
    // stage K tile (2x 64x32) and Vt tile (2x 64x32) via global_load_lds w=16
    for (int c = 0; c < 4; ++c) {
      int g = wave * 4 + c;            // 0..15
      const __bf16* src;
      __bf16* dst;
      if (g < 8) {
        int kk = g >> 2, seg = g & 3;
        int sk = seg * 16 + (lane >> 2);
        src = Kb + (size_t)(s0 + sk) * 1536 + kk * 32 + (lane & 3) * 8;
        dst = Ks[kk] + seg * 512;
      } else {
        int g2 = g - 8;
        int kk = g2 >> 2, seg = g2 & 3;
        int d = seg * 16 + (lane >> 2);
        src = Vtb + (size_t)d * 512 + s0 + kk * 32 + (lane & 3) * 8;
        dst = Vs[kk] + seg * 512;
      }
      gload_lds16(src, dst + lane * 8);
    }
    __syncthreads();

    float nk[4];
    for (int j = 0; j < 4; ++j) nk[j] = nkbase[s0 + j * 16 + l15];

    for (int ch = 0; ch < 4; ++ch) {
      // QK^T scores: 16 q x 64 k
      floatx4 z[4];
      for (int j = 0; j < 4; ++j) {
        bf16x8 b0 = *(const bf16x8*)(Ks[0] + (j * 16 + l15) * 32 + quad * 8);
        bf16x8 b1 = *(const bf16x8*)(Ks[1] + (j * 16 + l15) * 32 + quad * 8);
        floatx4 zz = zero;
        zz = __builtin_amdgcn_mfma_f32_16x16x32_bf16(aq[ch][0], b0, zz, 0, 0, 0);
        zz = __builtin_amdgcn_mfma_f32_16x16x32_bf16(aq[ch][1], b1, zz, 0, 0, 0);
        z[j] = zz;
      }
      // bounded softmax numerator (|s| <= ~1/8: no max subtraction needed)
      for (int j = 0; j < 4; ++j)
        for (int r = 0; r < 4; ++r) {
          float den = nq[ch][r] * nk[j];
          den = den > COS_EPS ? den : COS_EPS;
          float p = __expf(z[j][r] * __builtin_amdgcn_rcpf(den) * INV_TEMP);
          lsum[ch][r] += p;
          Pw[(quad * 4 + r) * 72 + j * 16 + l15] = (__bf16)p;
        }
      // P·V (wave-private P; compiler inserts lgkm waits)
      bf16x8 ap0 = *(const bf16x8*)(Pw + l15 * 72 + quad * 8);
      bf16x8 ap1 = *(const bf16x8*)(Pw + l15 * 72 + 32 + quad * 8);
      for (int jd = 0; jd < 4; ++jd) {
        bf16x8 v0 = *(const bf16x8*)(Vs[0] + (jd * 16 + l15) * 32 + quad * 8);
        bf16x8 v1 = *(const bf16x8*)(Vs[1] + (jd * 16 + l15) * 32 + quad * 8);
        o[ch][jd] = __builtin_amdgcn_mfma_f32_16x16x32_bf16(ap0, v0, o[ch][jd], 0, 0, 0);
        o[ch][jd] = __builtin_amdgcn_mfma_f32_16x16x32_bf16(ap1, v1, o[ch][jd], 0, 0, 0);
      }
    }
  }

  // reduce row sums across the 16 column-lanes
  for (int ch = 0; ch < 4; ++ch)
    for (int r = 0; r < 4; ++r) {
      float s = lsum[ch][r];
      for (int m = 1; m < 16; m <<= 1) s += __shfl_xor(s, m, 64);
      lsum[ch][r] = __builtin_amdgcn_rcpf(s);
    }
  for (int ch = 0; ch < 4; ++ch)
    for (int jd = 0; jd < 4; ++jd)
      for (int r = 0; r < 4; ++r) {
        int q = qbase + ch * 16 + quad * 4 + r;
        int d = jd * 16 + l15;
        out[(size_t)(b * 512 + q) * 512 + h * 64 + d] = (__bf16)(o[ch][jd][r] * lsum[ch][r]);
      }
}

// ---------------------------------------------------------------- residual + layernorm
template <bool WB>
__global__ __launch_bounds__(256) void resid_ln(const float* __restrict__ X1,
                                                const float* __restrict__ X2,
                                                const float* __restrict__ g,
                                                const float* __restrict__ be,
                                                float* __restrict__ outf,
                                                __bf16* __restrict__ outb) {
  int row = blockIdx.x * 4 + (threadIdx.x >> 6);
  int lane = threadIdx.x & 63;
  const float4* r1 = (const float4*)(X1 + (size_t)row * 512);
  const float4* r2 = (const float4*)(X2 + (size_t)row * 512);
  float4 a = r1[lane], b = r2[lane];
  float4 cc = r1[lane + 64], d = r2[lane + 64];
  float v[8] = {a.x + b.x, a.y + b.y, a.z + b.z, a.w + b.w,
                cc.x + d.x, cc.y + d.y, cc.z + d.z, cc.w + d.w};
  float s = 0.f, sq = 0.f;
  for (int i = 0; i < 8; ++i) {
    s += v[i];
    sq += v[i] * v[i];
  }
  for (int m = 1; m < 64; m <<= 1) {
    s += __shfl_xor(s, m, 64);
    sq += __shfl_xor(sq, m, 64);
  }
  float mean = s * (1.f / 512.f);
  float var = sq * (1.f / 512.f) - mean * mean;
  float rstd = rsqrtf(var + LN_EPS);
  float4 g0 = ((const float4*)g)[lane], g1 = ((const float4*)g)[lane + 64];
  float4 b0 = ((const float4*)be)[lane], b1 = ((const float4*)be)[lane + 64];
  float gg[8] = {g0.x, g0.y, g0.z, g0.w, g1.x, g1.y, g1.z, g1.w};
  float bb[8] = {b0.x, b0.y, b0.z, b0.w, b1.x, b1.y, b1.z, b1.w};
  float o[8];
  for (int i = 0; i < 8; ++i) o[i] = (v[i] - mean) * rstd * gg[i] + bb[i];
  float4 w0 = {o[0], o[1], o[2], o[3]}, w1 = {o[4], o[5], o[6], o[7]};
  ((float4*)(outf + (size_t)row * 512))[lane] = w0;
  ((float4*)(outf + (size_t)row * 512))[lane + 64] = w1;
  if (WB) {
    __bf16* ob = outb + (size_t)row * 512;
    for (int i = 0; i < 4; ++i) ob[lane * 4 + i] = (__bf16)o[i];
    for (int i = 0; i < 4; ++i) ob[256 + lane * 4 + i] = (__bf16)o[4 + i];
  }
}

// ---------------------------------------------------------------- launcher
extern "C" void kernel_launch(void* const* d_in, const int* in_sizes, int n_in,
                              void* d_out, int out_size, void* d_ws, size_t ws_size,
                              hipStream_t stream) {
  const float* x     = (const float*)d_in[0];
  const float* w_q   = (const float*)d_in[1];
  const float* w_k   = (const float*)d_in[2];
  const float* w_v   = (const float*)d_in[3];
  const float* w_o   = (const float*)d_in[4];
  const float* w_ff1 = (const float*)d_in[5];
  const float* b_ff1 = (const float*)d_in[6];
  const float* w_ff2 = (const float*)d_in[7];
  const float* b_ff2 = (const float*)d_in[8];
  const float* g1    = (const float*)d_in[9];
  const float* b1    = (const float*)d_in[10];
  const float* g2    = (const float*)d_in[11];
  const float* b2    = (const float*)d_in[12];
  float* out = (float*)d_out;

  char* ws = (char*)d_ws;
  size_t off = 0;
  auto alloc = [&](size_t bytes) -> void* {
    void* p = ws + off;
    off += (bytes + 255) & ~(size_t)255;
    return p;
  };
  __bf16* xb     = (__bf16*)alloc((size_t)Mrows * 512 * 2);
  __bf16* wt_qkv = (__bf16*)alloc((size_t)1536 * 512 * 2);
  __bf16* wt_o   = (__bf16*)alloc((size_t)512 * 512 * 2);
  __bf16* wt_ff1 = (__bf16*)alloc((size_t)2048 * 512 * 2);
  __bf16* wt_ff2 = (__bf16*)alloc((size_t)512 * 2048 * 2);
  __bf16* qkv    = (__bf16*)alloc((size_t)Mrows * 1536 * 2);
  float*  norms  = (float*)alloc((size_t)262144 * 4);
  __bf16* attn   = (__bf16*)alloc((size_t)Mrows * 512 * 2);
  float*  proj   = (float*)alloc((size_t)Mrows * 512 * 4);   // reused as ffn out
  float*  h1f    = (float*)alloc((size_t)Mrows * 512 * 4);
  __bf16* h1b    = (__bf16*)alloc((size_t)Mrows * 512 * 2);
  __bf16* mid    = (__bf16*)alloc((size_t)Mrows * 2048 * 2);
  __bf16* vtg    = mid;   // alias: vtg (16.7 MB) is dead before ff1 writes mid

  convert_bf16<<<8192, 256, 0, stream>>>(x, xb, Mrows * 512 / 4);
  transpose_to_bf16<<<1024, 256, 0, stream>>>(w_q, wt_qkv, 512, 512);
  transpose_to_bf16<<<1024, 256, 0, stream>>>(w_k, wt_qkv + 512 * 512, 512, 512);
  transpose_to_bf16<<<1024, 256, 0, stream>>>(w_v, wt_qkv + 2 * 512 * 512, 512, 512);
  transpose_to_bf16<<<1024, 256, 0, stream>>>(w_o, wt_o, 512, 512);
  transpose_to_bf16<<<4096, 256, 0, stream>>>(w_ff1, wt_ff1, 512, 2048);
  transpose_to_bf16<<<4096, 256, 0, stream>>>(w_ff2, wt_ff2, 2048, 512);

  gemm_bt<0><<<dim3(12, 128), 256, 0, stream>>>(xb, wt_qkv, qkv, nullptr, 1536, 512);
  vtrans_kernel<<<dim3(8, 256), 256, 0, stream>>>(qkv, vtg);
  norms_kernel<<<16384, 256, 0, stream>>>(qkv, norms);
  attn_kernel<<<dim3(2, 256), 256, 0, stream>>>(qkv, vtg, norms, attn);
  gemm_bt<1><<<dim3(4, 128), 256, 0, stream>>>(attn, wt_o, proj, nullptr, 512, 512);
  resid_ln<true><<<4096, 256, 0, stream>>>(x, proj, g1, b1, h1f, h1b);
  gemm_bt<2><<<dim3(16, 128), 256, 0, stream>>>(h1b, wt_ff1, mid, b_ff1, 2048, 512);
  gemm_bt<3><<<dim3(4, 128), 256, 0, stream>>>(mid, wt_ff2, proj, b_ff2, 512, 2048);
  resid_ln<false><<<4096, 256, 0, stream>>>(h1f, proj, g2, b2, out, nullptr);
}

// Round 3
// 399.374 us; speedup vs baseline: 1.3760x; 1.0364x over previous
//
#include <hip/hip_runtime.h>
#include <cmath>

// ---------------------------------------------------------------- types
typedef __bf16 bf16x8 __attribute__((ext_vector_type(8)));
typedef float  floatx4 __attribute__((ext_vector_type(4)));

#define LN_EPS 1e-5f
#define COS_EPS 1e-8f
#define INV_TEMP 0.125f   // 1/sqrt(64)

// B=32 S=512 D=512 H=8 DK=DV=64 DFF=2048, M = B*S = 16384
static const int Mrows = 16384;

__device__ __forceinline__ void gload_lds16(const void* g, void* l) {
  __builtin_amdgcn_global_load_lds(
      (const __attribute__((address_space(1))) void*)g,
      (__attribute__((address_space(3))) void*)l, 16, 0, 0);
}

// ---------------------------------------------------------------- prep kernels
__global__ __launch_bounds__(256) void convert_bf16(const float* __restrict__ src,
                                                    __bf16* __restrict__ dst, int n4) {
  int i = blockIdx.x * 256 + threadIdx.x;
  if (i < n4) {
    float4 v = ((const float4*)src)[i];
    dst[i * 4 + 0] = (__bf16)v.x;
    dst[i * 4 + 1] = (__bf16)v.y;
    dst[i * 4 + 2] = (__bf16)v.z;
    dst[i * 4 + 3] = (__bf16)v.w;
  }
}

// tiled transpose: src fp32 [R,C] -> dst bf16 [C,R]; R,C multiples of 64
__global__ __launch_bounds__(256) void tr_kernel(const float* __restrict__ src,
                                                 __bf16* __restrict__ dst,
                                                 int R, int C) {
  __shared__ __bf16 til[64][72];   // [c][r], +8 pad
  const int tid = threadIdx.x;
  const int bx = blockIdx.x;       // C/64
  const int by = blockIdx.y;       // R/64
  const float* s = src + (size_t)(by * 64) * C + bx * 64;
  int r = tid >> 4, c4 = (tid & 15) * 4;
  for (int p = 0; p < 4; ++p) {
    int rr = r + p * 16;
    float4 v = *(const float4*)(s + (size_t)rr * C + c4);
    til[c4 + 0][rr] = (__bf16)v.x;
    til[c4 + 1][rr] = (__bf16)v.y;
    til[c4 + 2][rr] = (__bf16)v.z;
    til[c4 + 3][rr] = (__bf16)v.w;
  }
  __syncthreads();
  __bf16* d = dst + (size_t)(bx * 64) * R + by * 64;
  int orow = tid >> 3, oc8 = (tid & 7) * 8;
  for (int p = 0; p < 2; ++p) {
    int rr = orow + p * 32;
    *(bf16x8*)(d + (size_t)rr * R + oc8) = *(const bf16x8*)(&til[rr][oc8]);
  }
}

// ---------------------------------------------------------------- GEMM  C = A[M,K] * Bt[N,K]^T
// XCD swizzle: 1-D grid of nbn*128 blocks; id%8 pins same-m n-tiles to one XCD.
// EPI: 0 -> bf16 out, 1 -> f32 out (split-K partial: z picks Cv/Cv2), 2 -> +bias,relu -> bf16,
//      4 -> bf16 out + fused q/k norms
template <int EPI>
__global__ __launch_bounds__(256) void gemm_bt(const __bf16* __restrict__ A,
                                               const __bf16* __restrict__ Bt,
                                               void* __restrict__ Cv,
                                               void* __restrict__ Cv2,
                                               const float* __restrict__ bias,
                                               float* __restrict__ norms,
                                               int nbn, int Ndim, int Kdim, int kspan) {
  __shared__ __align__(16) __bf16 As[128 * 32];
  __shared__ __align__(16) __bf16 Bs[128 * 32];
  const int tid = threadIdx.x;
  const int wave = tid >> 6, lane = tid & 63;
  const int l15 = lane & 15, quad = lane >> 4;
  // swizzle decode
  const int id = blockIdx.x;
  const int xcd = id & 7, t = id >> 3;
  const int nblk = t % nbn, mblk = (t / nbn) * 8 + xcd;
  const int m0 = mblk * 128, n0 = nblk * 128;
  const int k0 = blockIdx.z * kspan;
  const int wrow = (wave >> 1) * 64, wcol = (wave & 1) * 64;

  floatx4 zero = {0.f, 0.f, 0.f, 0.f};
  floatx4 acc[4][4];
  for (int i = 0; i < 4; ++i)
    for (int j = 0; j < 4; ++j) acc[i][j] = zero;

  for (int kt = k0; kt < k0 + kspan; kt += 32) {
    __syncthreads();
    for (int c = 0; c < 4; ++c) {
      int g = wave * 4 + c;
      const __bf16* src;
      __bf16* dst;
      if (g < 8) {
        int row = m0 + g * 16 + (lane >> 2);
        src = A + (size_t)row * Kdim + kt + (lane & 3) * 8;
        dst = As + g * 512;
      } else {
        int g2 = g - 8;
        int row = n0 + g2 * 16 + (lane >> 2);
        src = Bt + (size_t)row * Kdim + kt + (lane & 3) * 8;
        dst = Bs + g2 * 512;
      }
      gload_lds16(src, dst + lane * 8);
    }
    __syncthreads();
    bf16x8 a[4], b[4];
    for (int i = 0; i < 4; ++i)
      a[i] = *(const bf16x8*)(As + (wrow + i * 16 + l15) * 32 + quad * 8);
    for (int j = 0; j < 4; ++j)
      b[j] = *(const bf16x8*)(Bs + (wcol + j * 16 + l15) * 32 + quad * 8);
    for (int i = 0; i < 4; ++i)
      for (int j = 0; j < 4; ++j)
        acc[i][j] = __builtin_amdgcn_mfma_f32_16x16x32_bf16(a[i], b[j], acc[i][j], 0, 0, 0);
  }

  // fused q/k norms for the QKV GEMM (cols 0..511 = q heads, 512..1023 = k heads)
  if (EPI == 4) {
    int head_global = (n0 + wcol) >> 6;   // 64-col aligned -> exact head
    int kind = head_global >> 3;          // 0=q 1=k 2=v
    if (kind < 2) {
      int h = head_global & 7;
      for (int i = 0; i < 4; ++i)
        for (int r = 0; r < 4; ++r) {
          float sq = 0.f;
          for (int j = 0; j < 4; ++j) {
            float v = acc[i][j][r];
            sq += v * v;
          }
          for (int m = 1; m < 16; m <<= 1) sq += __shfl_xor(sq, m, 64);
          if (l15 == 0) {
            int arow = m0 + wrow + i * 16 + quad * 4 + r;
            int bb = arow >> 9, ss = arow & 511;
            norms[kind * 131072 + ((bb << 3) + h) * 512 + ss] = sqrtf(sq);
          }
        }
    }
  }

  float* outp = (float*)Cv;
  if (EPI == 1 && blockIdx.z != 0) outp = (float*)Cv2;

  for (int i = 0; i < 4; ++i)
    for (int j = 0; j < 4; ++j) {
      int row = m0 + wrow + i * 16 + quad * 4;
      int col = n0 + wcol + j * 16 + l15;
      float bv = (EPI == 2) ? bias[col] : 0.f;
      for (int r = 0; r < 4; ++r) {
        float v = acc[i][j][r];
        size_t idx = (size_t)(row + r) * Ndim + col;
        if (EPI == 0 || EPI == 4) {
          ((__bf16*)Cv)[idx] = (__bf16)v;
        } else if (EPI == 1) {
          outp[idx] = v;
        } else {  // EPI == 2
          v += bv;
          v = v > 0.f ? v : 0.f;
          ((__bf16*)Cv)[idx] = (__bf16)v;
        }
      }
    }
}

// ---------------------------------------------------------------- V transpose: qkv v-part -> Vt_g[bh][64][512]
__global__ __launch_bounds__(256) void vtrans_kernel(const __bf16* __restrict__ qkv,
                                                     __bf16* __restrict__ vtg) {
  __shared__ __align__(16) unsigned short til[64][68];
  const int tid = threadIdx.x;
  const int st = blockIdx.x;        // s-tile 0..7
  const int bh = blockIdx.y;        // 0..255
  const int b = bh >> 3, h = bh & 7;
  const unsigned short* src = (const unsigned short*)qkv +
      (size_t)(b * 512 + st * 64) * 1536 + 1024 + h * 64;
  for (int it = 0; it < 2; ++it) {
    int row = it * 32 + (tid >> 3);
    int c8 = (tid & 7) * 8;
    bf16x8 v = *(const bf16x8*)((const __bf16*)src + (size_t)row * 1536 + c8);
    for (int i = 0; i < 8; ++i) til[row][c8 + i] = ((unsigned short*)&v)[i];
  }
  __syncthreads();
  unsigned short* dst = (unsigned short*)vtg + (size_t)bh * 32768 + st * 64;
  for (int it = 0; it < 2; ++it) {
    int d = it * 32 + (tid >> 3);
    int s8 = (tid & 7) * 8;
    unsigned short v[8];
    for (int i = 0; i < 8; ++i) v[i] = til[s8 + i][d];
    *(bf16x8*)(dst + (size_t)d * 512 + s8) = *(bf16x8*)v;
  }
}

// ---------------------------------------------------------------- attention: block = (qhalf, bh)
__global__ __launch_bounds__(256) void attn_kernel(const __bf16* __restrict__ qkv,
                                                   const __bf16* __restrict__ vtg,
                                                   const float* __restrict__ norms,
                                                   __bf16* __restrict__ out) {
  __shared__ __align__(16) __bf16 Ks[2][64 * 32];
  __shared__ __align__(16) __bf16 Vs[2][64 * 32];
  __shared__ __align__(16) __bf16 P[4][16 * 72];
  const int tid = threadIdx.x, wave = tid >> 6, lane = tid & 63;
  const int l15 = lane & 15, quad = lane >> 4;
  const int qh = blockIdx.x;
  const int bh = blockIdx.y;
  const int b = bh >> 3, h = bh & 7;
  const int qbase = qh * 256 + wave * 64;

  const __bf16* Qb = qkv + (size_t)(b * 512) * 1536 + h * 64;
  const __bf16* Kb = Qb + 512;
  const __bf16* Vtb = vtg + (size_t)bh * 32768;
  const float* nkbase = norms + 131072 + bh * 512;
  __bf16* Pw = P[wave];

  bf16x8 aq[4][2];
  float nq[4][4];
  for (int ch = 0; ch < 4; ++ch) {
    int qrow = qbase + ch * 16;
    aq[ch][0] = *(const bf16x8*)(Qb + (size_t)(qrow + l15) * 1536 + quad * 8);
    aq[ch][1] = *(const bf16x8*)(Qb + (size_t)(qrow + l15) * 1536 + 32 + quad * 8);
    for (int r = 0; r < 4; ++r) nq[ch][r] = norms[bh * 512 + qrow + quad * 4 + r];
  }

  floatx4 zero = {0.f, 0.f, 0.f, 0.f};
  floatx4 o[4][4];
  float lsum[4][4];
  for (int ch = 0; ch < 4; ++ch)
    for (int jd = 0; jd < 4; ++jd) o[ch][jd] = zero;
  for (int ch = 0; ch < 4; ++ch)
    for (int r = 0; r < 4; ++r) lsum[ch][r] = 0.f;

  for (int kt = 0; kt < 8; ++kt) {
    int s0 = kt * 64;
    __syncthreads();
    for (int c = 0; c < 4; ++c) {
      int g = wave * 4 + c;
      const __bf16* src;
      __bf16* dst;
      if (g < 8) {
        int kk = g >> 2, seg = g & 3;
        int sk = seg * 16 + (lane >> 2);
        src = Kb + (size_t)(s0 + sk) * 1536 + kk * 32 + (lane & 3) * 8;
        dst = Ks[kk] + seg * 512;
      } else {
        int g2 = g - 8;
        int kk = g2 >> 2, seg = g2 & 3;
        int d = seg * 16 + (lane >> 2);
        src = Vtb + (size_t)d * 512 + s0 + kk * 32 + (lane & 3) * 8;
        dst = Vs[kk] + seg * 512;
      }
      gload_lds16(src, dst + lane * 8);
    }
    __syncthreads();

    float nk[4];
    for (int j = 0; j < 4; ++j) nk[j] = nkbase[s0 + j * 16 + l15];

    for (int ch = 0; ch < 4; ++ch) {
      floatx4 z[4];
      for (int j = 0; j < 4; ++j) {
        bf16x8 b0 = *(const bf16x8*)(Ks[0] + (j * 16 + l15) * 32 + quad * 8);
        bf16x8 b1 = *(const bf16x8*)(Ks[1] + (j * 16 + l15) * 32 + quad * 8);
        floatx4 zz = zero;
        zz = __builtin_amdgcn_mfma_f32_16x16x32_bf16(aq[ch][0], b0, zz, 0, 0, 0);
        zz = __builtin_amdgcn_mfma_f32_16x16x32_bf16(aq[ch][1], b1, zz, 0, 0, 0);
        z[j] = zz;
      }
      for (int j = 0; j < 4; ++j)
        for (int r = 0; r < 4; ++r) {
          float den = nq[ch][r] * nk[j];
          den = den > COS_EPS ? den : COS_EPS;
          float p = __expf(z[j][r] * __builtin_amdgcn_rcpf(den) * INV_TEMP);
          lsum[ch][r] += p;
          Pw[(quad * 4 + r) * 72 + j * 16 + l15] = (__bf16)p;
        }
      bf16x8 ap0 = *(const bf16x8*)(Pw + l15 * 72 + quad * 8);
      bf16x8 ap1 = *(const bf16x8*)(Pw + l15 * 72 + 32 + quad * 8);
      for (int jd = 0; jd < 4; ++jd) {
        bf16x8 v0 = *(const bf16x8*)(Vs[0] + (jd * 16 + l15) * 32 + quad * 8);
        bf16x8 v1 = *(const bf16x8*)(Vs[1] + (jd * 16 + l15) * 32 + quad * 8);
        o[ch][jd] = __builtin_amdgcn_mfma_f32_16x16x32_bf16(ap0, v0, o[ch][jd], 0, 0, 0);
        o[ch][jd] = __builtin_amdgcn_mfma_f32_16x16x32_bf16(ap1, v1, o[ch][jd], 0, 0, 0);
      }
    }
  }

  for (int ch = 0; ch < 4; ++ch)
    for (int r = 0; r < 4; ++r) {
      float s = lsum[ch][r];
      for (int m = 1; m < 16; m <<= 1) s += __shfl_xor(s, m, 64);
      lsum[ch][r] = __builtin_amdgcn_rcpf(s);
    }
  for (int ch = 0; ch < 4; ++ch)
    for (int jd = 0; jd < 4; ++jd)
      for (int r = 0; r < 4; ++r) {
        int q = qbase + ch * 16 + quad * 4 + r;
        int d = jd * 16 + l15;
        out[(size_t)(b * 512 + q) * 512 + h * 64 + d] = (__bf16)(o[ch][jd][r] * lsum[ch][r]);
      }
}

// ---------------------------------------------------------------- residual(+split-K partials) + layernorm
template <bool WB>
__global__ __launch_bounds__(256) void resid_ln(const float* __restrict__ X1,
                                                const float* __restrict__ X2,
                                                const float* __restrict__ X3,
                                                const float* __restrict__ bias,
                                                const float* __restrict__ g,
                                                const float* __restrict__ be,
                                                float* __restrict__ outf,
                                                __bf16* __restrict__ outb) {
  int row = blockIdx.x * 4 + (threadIdx.x >> 6);
  int lane = threadIdx.x & 63;
  const float4* r1 = (const float4*)(X1 + (size_t)row * 512);
  const float4* r2 = (const float4*)(X2 + (size_t)row * 512);
  const float4* r3 = (const float4*)(X3 + (size_t)row * 512);
  float4 a = r1[lane], b = r2[lane], e = r3[lane];
  float4 cc = r1[lane + 64], d = r2[lane + 64], f = r3[lane + 64];
  float v[8] = {a.x + b.x + e.x, a.y + b.y + e.y, a.z + b.z + e.z, a.w + b.w + e.w,
                cc.x + d.x + f.x, cc.y + d.y + f.y, cc.z + d.z + f.z, cc.w + d.w + f.w};
  if (bias) {
    float4 q0 = ((const float4*)bias)[lane], q1 = ((const float4*)bias)[lane + 64];
    v[0] += q0.x; v[1] += q0.y; v[2] += q0.z; v[3] += q0.w;
    v[4] += q1.x; v[5] += q1.y; v[6] += q1.z; v[7] += q1.w;
  }
  float s = 0.f, sq = 0.f;
  for (int i = 0; i < 8; ++i) {
    s += v[i];
    sq += v[i] * v[i];
  }
  for (int m = 1; m < 64; m <<= 1) {
    s += __shfl_xor(s, m, 64);
    sq += __shfl_xor(sq, m, 64);
  }
  float mean = s * (1.f / 512.f);
  float var = sq * (1.f / 512.f) - mean * mean;
  float rstd = rsqrtf(var + LN_EPS);
  float4 g0 = ((const float4*)g)[lane], g1 = ((const float4*)g)[lane + 64];
  float4 b0 = ((const float4*)be)[lane], b1 = ((const float4*)be)[lane + 64];
  float gg[8] = {g0.x, g0.y, g0.z, g0.w, g1.x, g1.y, g1.z, g1.w};
  float bb[8] = {b0.x, b0.y, b0.z, b0.w, b1.x, b1.y, b1.z, b1.w};
  float o[8];
  for (int i = 0; i < 8; ++i) o[i] = (v[i] - mean) * rstd * gg[i] + bb[i];
  float4 w0 = {o[0], o[1], o[2], o[3]}, w1 = {o[4], o[5], o[6], o[7]};
  ((float4*)(outf + (size_t)row * 512))[lane] = w0;
  ((float4*)(outf + (size_t)row * 512))[lane + 64] = w1;
  if (WB) {
    __bf16* ob = outb + (size_t)row * 512;
    for (int i = 0; i < 4; ++i) ob[lane * 4 + i] = (__bf16)o[i];
    for (int i = 0; i < 4; ++i) ob[256 + lane * 4 + i] = (__bf16)o[4 + i];
  }
}

// ---------------------------------------------------------------- launcher
extern "C" void kernel_launch(void* const* d_in, const int* in_sizes, int n_in,
                              void* d_out, int out_size, void* d_ws, size_t ws_size,
                              hipStream_t stream) {
  const float* x     = (const float*)d_in[0];
  const float* w_q   = (const float*)d_in[1];
  const float* w_k   = (const float*)d_in[2];
  const float* w_v   = (const float*)d_in[3];
  const float* w_o   = (const float*)d_in[4];
  const float* w_ff1 = (const float*)d_in[5];
  const float* b_ff1 = (const float*)d_in[6];
  const float* w_ff2 = (const float*)d_in[7];
  const float* b_ff2 = (const float*)d_in[8];
  const float* g1    = (const float*)d_in[9];
  const float* b1    = (const float*)d_in[10];
  const float* g2    = (const float*)d_in[11];
  const float* b2    = (const float*)d_in[12];
  float* out = (float*)d_out;

  char* ws = (char*)d_ws;
  size_t off = 0;
  auto alloc = [&](size_t bytes) -> void* {
    void* p = ws + off;
    off += (bytes + 255) & ~(size_t)255;
    return p;
  };
  __bf16* xb     = (__bf16*)alloc((size_t)Mrows * 512 * 2);
  __bf16* wt_qkv = (__bf16*)alloc((size_t)1536 * 512 * 2);
  __bf16* wt_o   = (__bf16*)alloc((size_t)512 * 512 * 2);
  __bf16* wt_ff1 = (__bf16*)alloc((size_t)2048 * 512 * 2);
  __bf16* wt_ff2 = (__bf16*)alloc((size_t)512 * 2048 * 2);
  __bf16* qkv    = (__bf16*)alloc((size_t)Mrows * 1536 * 2);
  float*  norms  = (float*)alloc((size_t)262144 * 4);
  __bf16* attn   = (__bf16*)alloc((size_t)Mrows * 512 * 2);
  float*  proj   = (float*)alloc((size_t)Mrows * 512 * 4);
  float*  h1f    = (float*)alloc((size_t)Mrows * 512 * 4);
  __bf16* h1b    = (__bf16*)alloc((size_t)Mrows * 512 * 2);
  __bf16* mid    = (__bf16*)alloc((size_t)Mrows * 2048 * 2);
  __bf16* vtg    = mid;            // alias: dead before ff1 writes mid
  float*  part1  = (float*)qkv;    // alias: 33.6 MB partial; qkv dead after attn

  convert_bf16<<<8192, 256, 0, stream>>>(x, xb, Mrows * 512 / 4);
  tr_kernel<<<dim3(8, 8), 256, 0, stream>>>(w_q, wt_qkv, 512, 512);
  tr_kernel<<<dim3(8, 8), 256, 0, stream>>>(w_k, wt_qkv + 512 * 512, 512, 512);
  tr_kernel<<<dim3(8, 8), 256, 0, stream>>>(w_v, wt_qkv + 2 * 512 * 512, 512, 512);
  tr_kernel<<<dim3(8, 8), 256, 0, stream>>>(w_o, wt_o, 512, 512);
  tr_kernel<<<dim3(32, 8), 256, 0, stream>>>(w_ff1, wt_ff1, 512, 2048);
  tr_kernel<<<dim3(8, 32), 256, 0, stream>>>(w_ff2, wt_ff2, 2048, 512);

  // QKV: 12 n-tiles x 128 m-tiles, fused norms
  gemm_bt<4><<<dim3(12 * 128), 256, 0, stream>>>(xb, wt_qkv, qkv, nullptr, nullptr,
                                                 norms, 12, 1536, 512, 512);
  vtrans_kernel<<<dim3(8, 256), 256, 0, stream>>>(qkv, vtg);
  attn_kernel<<<dim3(2, 256), 256, 0, stream>>>(qkv, vtg, norms, attn);
  // w_o proj: split-K=2 (K=256 each), partials -> proj, part1
  gemm_bt<1><<<dim3(4 * 128, 1, 2), 256, 0, stream>>>(attn, wt_o, proj, part1, nullptr,
                                                      nullptr, 4, 512, 512, 256);
  resid_ln<true><<<4096, 256, 0, stream>>>(x, proj, part1, nullptr, g1, b1, h1f, h1b);
  // FFN1
  gemm_bt<2><<<dim3(16 * 128), 256, 0, stream>>>(h1b, wt_ff1, mid, nullptr, b_ff1,
                                                 nullptr, 16, 2048, 512, 512);
  // FFN2: split-K=2 (K=1024 each), partials -> proj, part1; bias folded into LN2
  gemm_bt<1><<<dim3(4 * 128, 1, 2), 256, 0, stream>>>(mid, wt_ff2, proj, part1, nullptr,
                                                      nullptr, 4, 512, 2048, 1024);
  resid_ln<false><<<4096, 256, 0, stream>>>(h1f, proj, part1, b_ff2, g2, b2, out, nullptr);
}

// Round 4
// 372.882 us; speedup vs baseline: 1.4738x; 1.0710x over previous
//
#include <hip/hip_runtime.h>
#include <cmath>

// ---------------------------------------------------------------- types
typedef __bf16 bf16x8 __attribute__((ext_vector_type(8)));
typedef float  floatx4 __attribute__((ext_vector_type(4)));

#define LN_EPS 1e-5f
#define COS_EPS 1e-8f
#define INV_TEMP 0.125f   // 1/sqrt(64)

// B=32 S=512 D=512 H=8 DK=DV=64 DFF=2048, M = B*S = 16384
static const int Mrows = 16384;

__device__ __forceinline__ void gload_lds16(const void* g, void* l) {
  __builtin_amdgcn_global_load_lds(
      (const __attribute__((address_space(1))) void*)g,
      (__attribute__((address_space(3))) void*)l, 16, 0, 0);
}

// ---------------------------------------------------------------- prep kernels
__global__ __launch_bounds__(256) void convert_bf16(const float* __restrict__ src,
                                                    __bf16* __restrict__ dst, int n4) {
  int i = blockIdx.x * 256 + threadIdx.x;
  if (i < n4) {
    float4 v = ((const float4*)src)[i];
    dst[i * 4 + 0] = (__bf16)v.x;
    dst[i * 4 + 1] = (__bf16)v.y;
    dst[i * 4 + 2] = (__bf16)v.z;
    dst[i * 4 + 3] = (__bf16)v.w;
  }
}

// tiled transpose: src fp32 [R,C] -> dst bf16 [C,R]; R,C multiples of 64
__global__ __launch_bounds__(256) void tr_kernel(const float* __restrict__ src,
                                                 __bf16* __restrict__ dst,
                                                 int R, int C) {
  __shared__ __bf16 til[64][72];
  const int tid = threadIdx.x;
  const int bx = blockIdx.x;
  const int by = blockIdx.y;
  const float* s = src + (size_t)(by * 64) * C + bx * 64;
  int r = tid >> 4, c4 = (tid & 15) * 4;
  for (int p = 0; p < 4; ++p) {
    int rr = r + p * 16;
    float4 v = *(const float4*)(s + (size_t)rr * C + c4);
    til[c4 + 0][rr] = (__bf16)v.x;
    til[c4 + 1][rr] = (__bf16)v.y;
    til[c4 + 2][rr] = (__bf16)v.z;
    til[c4 + 3][rr] = (__bf16)v.w;
  }
  __syncthreads();
  __bf16* d = dst + (size_t)(bx * 64) * R + by * 64;
  int orow = tid >> 3, oc8 = (tid & 7) * 8;
  for (int p = 0; p < 2; ++p) {
    int rr = orow + p * 32;
    *(bf16x8*)(d + (size_t)rr * R + oc8) = *(const bf16x8*)(&til[rr][oc8]);
  }
}

// ---------------------------------------------------------------- GEMM  C = A[M,K] * Bt[N,K]^T
// BK=64, 128B LDS rows with 16B-slot XOR swizzle (slot ^= row&7) -> conflict-free b128 reads.
// XCD swizzle: 1-D grid; id%8 pins same-m n-tiles to one XCD.
// EPI: 1 -> f32 out (z picks Cv/Cv2), 2 -> +bias,relu -> bf16, 4 -> bf16 out + fused q/k norms
template <int EPI>
__global__ __launch_bounds__(256) void gemm_bt(const __bf16* __restrict__ A,
                                               const __bf16* __restrict__ Bt,
                                               void* __restrict__ Cv,
                                               void* __restrict__ Cv2,
                                               const float* __restrict__ bias,
                                               float* __restrict__ norms,
                                               int nbn, int Ndim, int Kdim, int kspan) {
  __shared__ __align__(16) __bf16 As[128 * 64];
  __shared__ __align__(16) __bf16 Bs[128 * 64];
  const int tid = threadIdx.x;
  const int wave = tid >> 6, lane = tid & 63;
  const int l15 = lane & 15, quad = lane >> 4;
  const int id = blockIdx.x;
  const int xcd = id & 7, t = id >> 3;
  const int nblk = t % nbn, mblk = (t / nbn) * 8 + xcd;
  const int m0 = mblk * 128, n0 = nblk * 128;
  const int k0 = blockIdx.z * kspan;
  const int wrow = (wave >> 1) * 64, wcol = (wave & 1) * 64;
  const int rs = lane >> 3;              // row within 8-row chunk
  const int swz_st = ((lane & 7) ^ rs) * 8;  // swizzled global k-offset for staging
  const int s7 = l15 & 7;                // read-side swizzle key

  floatx4 zero = {0.f, 0.f, 0.f, 0.f};
  floatx4 acc[4][4];
  for (int i = 0; i < 4; ++i)
    for (int j = 0; j < 4; ++j) acc[i][j] = zero;

  for (int kt = k0; kt < k0 + kspan; kt += 64) {
    __syncthreads();
    // stage 32 KB: 32 chunks of 1KB (8 rows x 128B); wave w takes chunks w*8..w*8+7
    for (int c = 0; c < 8; ++c) {
      int g = wave * 8 + c;
      const __bf16* src;
      __bf16* dst;
      if (g < 16) {
        int row = m0 + g * 8 + rs;
        src = A + (size_t)row * Kdim + kt + swz_st;
        dst = As + g * 512;
      } else {
        int g2 = g - 16;
        int row = n0 + g2 * 8 + rs;
        src = Bt + (size_t)row * Kdim + kt + swz_st;
        dst = Bs + g2 * 512;
      }
      gload_lds16(src, dst + lane * 8);
    }
    __syncthreads();
    for (int hh = 0; hh < 2; ++hh) {
      int ko = ((hh * 4 + quad) ^ s7) * 8;
      bf16x8 a[4], b[4];
      for (int i = 0; i < 4; ++i)
        a[i] = *(const bf16x8*)(As + (wrow + i * 16 + l15) * 64 + ko);
      for (int j = 0; j < 4; ++j)
        b[j] = *(const bf16x8*)(Bs + (wcol + j * 16 + l15) * 64 + ko);
      for (int i = 0; i < 4; ++i)
        for (int j = 0; j < 4; ++j)
          acc[i][j] = __builtin_amdgcn_mfma_f32_16x16x32_bf16(a[i], b[j], acc[i][j], 0, 0, 0);
    }
  }

  // fused q/k norms for the QKV GEMM (cols 0..511 = q heads, 512..1023 = k heads)
  if (EPI == 4) {
    int head_global = (n0 + wcol) >> 6;
    int kind = head_global >> 3;          // 0=q 1=k 2=v
    if (kind < 2) {
      int h = head_global & 7;
      for (int i = 0; i < 4; ++i)
        for (int r = 0; r < 4; ++r) {
          float sq = 0.f;
          for (int j = 0; j < 4; ++j) {
            float v = acc[i][j][r];
            sq += v * v;
          }
          for (int m = 1; m < 16; m <<= 1) sq += __shfl_xor(sq, m, 64);
          if (l15 == 0) {
            int arow = m0 + wrow + i * 16 + quad * 4 + r;
            int bb = arow >> 9, ss = arow & 511;
            norms[kind * 131072 + ((bb << 3) + h) * 512 + ss] = sqrtf(sq);
          }
        }
    }
  }

  float* outp = (float*)Cv;
  if (EPI == 1 && blockIdx.z != 0) outp = (float*)Cv2;

  for (int i = 0; i < 4; ++i)
    for (int j = 0; j < 4; ++j) {
      int row = m0 + wrow + i * 16 + quad * 4;
      int col = n0 + wcol + j * 16 + l15;
      float bv = (EPI == 2) ? bias[col] : 0.f;
      for (int r = 0; r < 4; ++r) {
        float v = acc[i][j][r];
        size_t idx = (size_t)(row + r) * Ndim + col;
        if (EPI == 4) {
          ((__bf16*)Cv)[idx] = (__bf16)v;
        } else if (EPI == 1) {
          outp[idx] = v;
        } else {  // EPI == 2
          v += bv;
          v = v > 0.f ? v : 0.f;
          ((__bf16*)Cv)[idx] = (__bf16)v;
        }
      }
    }
}

// ---------------------------------------------------------------- V transpose: qkv v-part -> Vt_g[bh][64][512]
__global__ __launch_bounds__(256) void vtrans_kernel(const __bf16* __restrict__ qkv,
                                                     __bf16* __restrict__ vtg) {
  __shared__ __align__(16) unsigned short til[64][68];
  const int tid = threadIdx.x;
  const int st = blockIdx.x;
  const int bh = blockIdx.y;
  const int b = bh >> 3, h = bh & 7;
  const unsigned short* src = (const unsigned short*)qkv +
      (size_t)(b * 512 + st * 64) * 1536 + 1024 + h * 64;
  for (int it = 0; it < 2; ++it) {
    int row = it * 32 + (tid >> 3);
    int c8 = (tid & 7) * 8;
    bf16x8 v = *(const bf16x8*)((const __bf16*)src + (size_t)row * 1536 + c8);
    for (int i = 0; i < 8; ++i) til[row][c8 + i] = ((unsigned short*)&v)[i];
  }
  __syncthreads();
  unsigned short* dst = (unsigned short*)vtg + (size_t)bh * 32768 + st * 64;
  for (int it = 0; it < 2; ++it) {
    int d = it * 32 + (tid >> 3);
    int s8 = (tid & 7) * 8;
    unsigned short v[8];
    for (int i = 0; i < 8; ++i) v[i] = til[s8 + i][d];
    *(bf16x8*)(dst + (size_t)d * 512 + s8) = *(bf16x8*)v;
  }
}

// ---------------------------------------------------------------- attention: block = (qhalf, bh)
// K/V tiles: [64][64] LDS rows (128B) with the same 16B-slot XOR swizzle -> conflict-free.
__global__ __launch_bounds__(256) void attn_kernel(const __bf16* __restrict__ qkv,
                                                   const __bf16* __restrict__ vtg,
                                                   const float* __restrict__ norms,
                                                   __bf16* __restrict__ out) {
  __shared__ __align__(16) __bf16 Ks[64 * 64];   // [sk][d]
  __shared__ __align__(16) __bf16 Vs[64 * 64];   // [d][sk]
  __shared__ __align__(16) __bf16 P[4][16 * 72];
  const int tid = threadIdx.x, wave = tid >> 6, lane = tid & 63;
  const int l15 = lane & 15, quad = lane >> 4;
  const int qh = blockIdx.x;
  const int bh = blockIdx.y;
  const int b = bh >> 3, h = bh & 7;
  const int qbase = qh * 256 + wave * 64;
  const int rs = lane >> 3;
  const int swz_st = ((lane & 7) ^ rs) * 8;
  const int s7 = l15 & 7;

  const __bf16* Qb = qkv + (size_t)(b * 512) * 1536 + h * 64;
  const __bf16* Kb = Qb + 512;
  const __bf16* Vtb = vtg + (size_t)bh * 32768;
  const float* nkbase = norms + 131072 + bh * 512;
  __bf16* Pw = P[wave];

  bf16x8 aq[4][2];
  float nq[4][4];
  for (int ch = 0; ch < 4; ++ch) {
    int qrow = qbase + ch * 16;
    aq[ch][0] = *(const bf16x8*)(Qb + (size_t)(qrow + l15) * 1536 + quad * 8);
    aq[ch][1] = *(const bf16x8*)(Qb + (size_t)(qrow + l15) * 1536 + 32 + quad * 8);
    for (int r = 0; r < 4; ++r) nq[ch][r] = norms[bh * 512 + qrow + quad * 4 + r];
  }

  floatx4 zero = {0.f, 0.f, 0.f, 0.f};
  floatx4 o[4][4];
  float lsum[4][4];
  for (int ch = 0; ch < 4; ++ch)
    for (int jd = 0; jd < 4; ++jd) o[ch][jd] = zero;
  for (int ch = 0; ch < 4; ++ch)
    for (int r = 0; r < 4; ++r) lsum[ch][r] = 0.f;

  for (int kt = 0; kt < 8; ++kt) {
    int s0 = kt * 64;
    __syncthreads();
    // stage K[64 sk][64 d] and Vt[64 d][64 sk]: 16 chunks of 1KB (8 rows x 128B)
    for (int c = 0; c < 4; ++c) {
      int g = wave * 4 + c;
      const __bf16* src;
      __bf16* dst;
      if (g < 8) {
        int sk = g * 8 + rs;
        src = Kb + (size_t)(s0 + sk) * 1536 + swz_st;
        dst = Ks + g * 512;
      } else {
        int g2 = g - 8;
        int d = g2 * 8 + rs;
        src = Vtb + (size_t)d * 512 + s0 + swz_st;
        dst = Vs + g2 * 512;
      }
      gload_lds16(src, dst + lane * 8);
    }
    __syncthreads();

    float nk[4];
    for (int j = 0; j < 4; ++j) nk[j] = nkbase[s0 + j * 16 + l15];

    for (int ch = 0; ch < 4; ++ch) {
      floatx4 z[4];
      for (int j = 0; j < 4; ++j) {
        int r64 = (j * 16 + l15) * 64;
        bf16x8 b0 = *(const bf16x8*)(Ks + r64 + ((quad ^ s7) * 8));
        bf16x8 b1 = *(const bf16x8*)(Ks + r64 + (((4 + quad) ^ s7) * 8));
        floatx4 zz = zero;
        zz = __builtin_amdgcn_mfma_f32_16x16x32_bf16(aq[ch][0], b0, zz, 0, 0, 0);
        zz = __builtin_amdgcn_mfma_f32_16x16x32_bf16(aq[ch][1], b1, zz, 0, 0, 0);
        z[j] = zz;
      }
      for (int j = 0; j < 4; ++j)
        for (int r = 0; r < 4; ++r) {
          float den = nq[ch][r] * nk[j];
          den = den > COS_EPS ? den : COS_EPS;
          float p = __expf(z[j][r] * __builtin_amdgcn_rcpf(den) * INV_TEMP);
          lsum[ch][r] += p;
          Pw[(quad * 4 + r) * 72 + j * 16 + l15] = (__bf16)p;
        }
      bf16x8 ap0 = *(const bf16x8*)(Pw + l15 * 72 + quad * 8);
      bf16x8 ap1 = *(const bf16x8*)(Pw + l15 * 72 + 32 + quad * 8);
      for (int jd = 0; jd < 4; ++jd) {
        int r64 = (jd * 16 + l15) * 64;
        bf16x8 v0 = *(const bf16x8*)(Vs + r64 + ((quad ^ s7) * 8));
        bf16x8 v1 = *(const bf16x8*)(Vs + r64 + (((4 + quad) ^ s7) * 8));
        o[ch][jd] = __builtin_amdgcn_mfma_f32_16x16x32_bf16(ap0, v0, o[ch][jd], 0, 0, 0);
        o[ch][jd] = __builtin_amdgcn_mfma_f32_16x16x32_bf16(ap1, v1, o[ch][jd], 0, 0, 0);
      }
    }
  }

  for (int ch = 0; ch < 4; ++ch)
    for (int r = 0; r < 4; ++r) {
      float s = lsum[ch][r];
      for (int m = 1; m < 16; m <<= 1) s += __shfl_xor(s, m, 64);
      lsum[ch][r] = __builtin_amdgcn_rcpf(s);
    }
  for (int ch = 0; ch < 4; ++ch)
    for (int jd = 0; jd < 4; ++jd)
      for (int r = 0; r < 4; ++r) {
        int q = qbase + ch * 16 + quad * 4 + r;
        int d = jd * 16 + l15;
        out[(size_t)(b * 512 + q) * 512 + h * 64 + d] = (__bf16)(o[ch][jd][r] * lsum[ch][r]);
      }
}

// ---------------------------------------------------------------- residual(+optional partial/bias) + layernorm
template <bool WB>
__global__ __launch_bounds__(256) void resid_ln(const float* __restrict__ X1,
                                                const float* __restrict__ X2,
                                                const float* __restrict__ X3,
                                                const float* __restrict__ bias,
                                                const float* __restrict__ g,
                                                const float* __restrict__ be,
                                                float* __restrict__ outf,
                                                __bf16* __restrict__ outb) {
  int row = blockIdx.x * 4 + (threadIdx.x >> 6);
  int lane = threadIdx.x & 63;
  const float4* r1 = (const float4*)(X1 + (size_t)row * 512);
  const float4* r2 = (const float4*)(X2 + (size_t)row * 512);
  float4 a = r1[lane], b = r2[lane];
  float4 cc = r1[lane + 64], d = r2[lane + 64];
  float v[8] = {a.x + b.x, a.y + b.y, a.z + b.z, a.w + b.w,
                cc.x + d.x, cc.y + d.y, cc.z + d.z, cc.w + d.w};
  if (X3) {
    const float4* r3 = (const float4*)(X3 + (size_t)row * 512);
    float4 e = r3[lane], f = r3[lane + 64];
    v[0] += e.x; v[1] += e.y; v[2] += e.z; v[3] += e.w;
    v[4] += f.x; v[5] += f.y; v[6] += f.z; v[7] += f.w;
  }
  if (bias) {
    float4 q0 = ((const float4*)bias)[lane], q1 = ((const float4*)bias)[lane + 64];
    v[0] += q0.x; v[1] += q0.y; v[2] += q0.z; v[3] += q0.w;
    v[4] += q1.x; v[5] += q1.y; v[6] += q1.z; v[7] += q1.w;
  }
  float s = 0.f, sq = 0.f;
  for (int i = 0; i < 8; ++i) {
    s += v[i];
    sq += v[i] * v[i];
  }
  for (int m = 1; m < 64; m <<= 1) {
    s += __shfl_xor(s, m, 64);
    sq += __shfl_xor(sq, m, 64);
  }
  float mean = s * (1.f / 512.f);
  float var = sq * (1.f / 512.f) - mean * mean;
  float rstd = rsqrtf(var + LN_EPS);
  float4 g0 = ((const float4*)g)[lane], g1 = ((const float4*)g)[lane + 64];
  float4 b0 = ((const float4*)be)[lane], b1 = ((const float4*)be)[lane + 64];
  float gg[8] = {g0.x, g0.y, g0.z, g0.w, g1.x, g1.y, g1.z, g1.w};
  float bb[8] = {b0.x, b0.y, b0.z, b0.w, b1.x, b1.y, b1.z, b1.w};
  float o[8];
  for (int i = 0; i < 8; ++i) o[i] = (v[i] - mean) * rstd * gg[i] + bb[i];
  float4 w0 = {o[0], o[1], o[2], o[3]}, w1 = {o[4], o[5], o[6], o[7]};
  ((float4*)(outf + (size_t)row * 512))[lane] = w0;
  ((float4*)(outf + (size_t)row * 512))[lane + 64] = w1;
  if (WB) {
    __bf16* ob = outb + (size_t)row * 512;
    for (int i = 0; i < 4; ++i) ob[lane * 4 + i] = (__bf16)o[i];
    for (int i = 0; i < 4; ++i) ob[256 + lane * 4 + i] = (__bf16)o[4 + i];
  }
}

// ---------------------------------------------------------------- launcher
extern "C" void kernel_launch(void* const* d_in, const int* in_sizes, int n_in,
                              void* d_out, int out_size, void* d_ws, size_t ws_size,
                              hipStream_t stream) {
  const float* x     = (const float*)d_in[0];
  const float* w_q   = (const float*)d_in[1];
  const float* w_k   = (const float*)d_in[2];
  const float* w_v   = (const float*)d_in[3];
  const float* w_o   = (const float*)d_in[4];
  const float* w_ff1 = (const float*)d_in[5];
  const float* b_ff1 = (const float*)d_in[6];
  const float* w_ff2 = (const float*)d_in[7];
  const float* b_ff2 = (const float*)d_in[8];
  const float* g1    = (const float*)d_in[9];
  const float* b1    = (const float*)d_in[10];
  const float* g2    = (const float*)d_in[11];
  const float* b2    = (const float*)d_in[12];
  float* out = (float*)d_out;

  char* ws = (char*)d_ws;
  size_t off = 0;
  auto alloc = [&](size_t bytes) -> void* {
    void* p = ws + off;
    off += (bytes + 255) & ~(size_t)255;
    return p;
  };
  __bf16* xb     = (__bf16*)alloc((size_t)Mrows * 512 * 2);
  __bf16* wt_qkv = (__bf16*)alloc((size_t)1536 * 512 * 2);
  __bf16* wt_o   = (__bf16*)alloc((size_t)512 * 512 * 2);
  __bf16* wt_ff1 = (__bf16*)alloc((size_t)2048 * 512 * 2);
  __bf16* wt_ff2 = (__bf16*)alloc((size_t)512 * 2048 * 2);
  __bf16* qkv    = (__bf16*)alloc((size_t)Mrows * 1536 * 2);
  float*  norms  = (float*)alloc((size_t)262144 * 4);
  __bf16* attn   = (__bf16*)alloc((size_t)Mrows * 512 * 2);
  float*  proj   = (float*)alloc((size_t)Mrows * 512 * 4);
  float*  h1f    = (float*)alloc((size_t)Mrows * 512 * 4);
  __bf16* h1b    = (__bf16*)alloc((size_t)Mrows * 512 * 2);
  __bf16* mid    = (__bf16*)alloc((size_t)Mrows * 2048 * 2);
  __bf16* vtg    = mid;            // alias: dead before ff1 writes mid
  float*  part1  = (float*)qkv;    // alias: qkv dead after attn

  convert_bf16<<<8192, 256, 0, stream>>>(x, xb, Mrows * 512 / 4);
  tr_kernel<<<dim3(8, 8), 256, 0, stream>>>(w_q, wt_qkv, 512, 512);
  tr_kernel<<<dim3(8, 8), 256, 0, stream>>>(w_k, wt_qkv + 512 * 512, 512, 512);
  tr_kernel<<<dim3(8, 8), 256, 0, stream>>>(w_v, wt_qkv + 2 * 512 * 512, 512, 512);
  tr_kernel<<<dim3(8, 8), 256, 0, stream>>>(w_o, wt_o, 512, 512);
  tr_kernel<<<dim3(32, 8), 256, 0, stream>>>(w_ff1, wt_ff1, 512, 2048);
  tr_kernel<<<dim3(8, 32), 256, 0, stream>>>(w_ff2, wt_ff2, 2048, 512);

  // QKV: 12 n-tiles x 128 m-tiles, fused norms
  gemm_bt<4><<<dim3(12 * 128), 256, 0, stream>>>(xb, wt_qkv, qkv, nullptr, nullptr,
                                                 norms, 12, 1536, 512, 512);
  vtrans_kernel<<<dim3(8, 256), 256, 0, stream>>>(qkv, vtg);
  attn_kernel<<<dim3(2, 256), 256, 0, stream>>>(qkv, vtg, norms, attn);
  // w_o proj: single-K (split-K was pure write overhead)
  gemm_bt<1><<<dim3(4 * 128), 256, 0, stream>>>(attn, wt_o, proj, nullptr, nullptr,
                                                nullptr, 4, 512, 512, 512);
  resid_ln<true><<<4096, 256, 0, stream>>>(x, proj, nullptr, nullptr, g1, b1, h1f, h1b);
  // FFN1
  gemm_bt<2><<<dim3(16 * 128), 256, 0, stream>>>(h1b, wt_ff1, mid, nullptr, b_ff1,
                                                 nullptr, 16, 2048, 512, 512);
  // FFN2: split-K=2 (K=1024 each), partials -> proj, part1; bias folded into LN2
  gemm_bt<1><<<dim3(4 * 128, 1, 2), 256, 0, stream>>>(mid, wt_ff2, proj, part1, nullptr,
                                                      nullptr, 4, 512, 2048, 1024);
  resid_ln<false><<<4096, 256, 0, stream>>>(h1f, proj, part1, b_ff2, g2, b2, out, nullptr);
}

// Round 5
// 349.199 us; speedup vs baseline: 1.5738x; 1.0678x over previous
//
#include <hip/hip_runtime.h>
#include <cmath>

// ---------------------------------------------------------------- types
typedef __bf16 bf16x8 __attribute__((ext_vector_type(8)));
typedef float  floatx4 __attribute__((ext_vector_type(4)));

#define LN_EPS 1e-5f
#define COS_EPS 1e-8f
#define INV_TEMP 0.125f   // 1/sqrt(64)

// B=32 S=512 D=512 H=8 DK=DV=64 DFF=2048, M = B*S = 16384
static const int Mrows = 16384;

__device__ __forceinline__ void gload_lds16(const void* g, void* l) {
  __builtin_amdgcn_global_load_lds(
      (const __attribute__((address_space(1))) void*)g,
      (__attribute__((address_space(3))) void*)l, 16, 0, 0);
}

// ---------------------------------------------------------------- fused prep: x->bf16 + 6 weight transposes
// blocks [0,8192): convert x (1024 floats/block)
// blocks [8192,8960): 64x64 transpose tiles: wq,wk,wv,wo (64 ea), wff1 (256), wff2 (256)
__global__ __launch_bounds__(256) void prep_kernel(const float* __restrict__ x, __bf16* __restrict__ xb,
                                                   const float* __restrict__ wq, const float* __restrict__ wk,
                                                   const float* __restrict__ wv, const float* __restrict__ wo,
                                                   const float* __restrict__ wff1, const float* __restrict__ wff2,
                                                   __bf16* __restrict__ tq, __bf16* __restrict__ tk,
                                                   __bf16* __restrict__ tv, __bf16* __restrict__ to_,
                                                   __bf16* __restrict__ tff1, __bf16* __restrict__ tff2) {
  const int bid = blockIdx.x, tid = threadIdx.x;
  if (bid < 8192) {
    int i = bid * 256 + tid;
    float4 v = ((const float4*)x)[i];
    __bf16* d = xb + i * 4;
    d[0] = (__bf16)v.x; d[1] = (__bf16)v.y; d[2] = (__bf16)v.z; d[3] = (__bf16)v.w;
    return;
  }
  __shared__ __bf16 til[64][72];
  int t = bid - 8192;
  const float* src; __bf16* dst; int R, C, bx, by;
  if (t < 256) {
    int w = t >> 6, tt = t & 63;
    const float* srcs[4] = {wq, wk, wv, wo};
    __bf16* dsts[4] = {tq, tk, tv, to_};
    src = srcs[w]; dst = dsts[w]; R = 512; C = 512; bx = tt & 7; by = tt >> 3;
  } else if (t < 512) {
    int tt = t - 256;
    src = wff1; dst = tff1; R = 512; C = 2048; bx = tt & 31; by = tt >> 5;
  } else {
    int tt = t - 512;
    src = wff2; dst = tff2; R = 2048; C = 512; bx = tt & 7; by = tt >> 3;
  }
  const float* s = src + (size_t)(by * 64) * C + bx * 64;
  int r = tid >> 4, c4 = (tid & 15) * 4;
  for (int p = 0; p < 4; ++p) {
    int rr = r + p * 16;
    float4 v = *(const float4*)(s + (size_t)rr * C + c4);
    til[c4 + 0][rr] = (__bf16)v.x;
    til[c4 + 1][rr] = (__bf16)v.y;
    til[c4 + 2][rr] = (__bf16)v.z;
    til[c4 + 3][rr] = (__bf16)v.w;
  }
  __syncthreads();
  __bf16* d = dst + (size_t)(bx * 64) * R + by * 64;
  int orow = tid >> 3, oc8 = (tid & 7) * 8;
  for (int p = 0; p < 2; ++p) {
    int rr = orow + p * 32;
    *(bf16x8*)(d + (size_t)rr * R + oc8) = *(const bf16x8*)(&til[rr][oc8]);
  }
}

// ---------------------------------------------------------------- GEMM  C = A[M,K] * Bt[N,K]^T
// BK=64, 128B LDS rows with 16B-slot XOR swizzle (slot ^= row&7) -> conflict-free b128 reads.
// XCD swizzle: 1-D grid; id%8 pins same-m n-tiles to one XCD.
// EPI: 1 -> f32 out, 2 -> +bias,relu -> bf16, 4 -> bf16 out + fused q/k norms
template <int EPI>
__global__ __launch_bounds__(256) void gemm_bt(const __bf16* __restrict__ A,
                                               const __bf16* __restrict__ Bt,
                                               void* __restrict__ Cv,
                                               const float* __restrict__ bias,
                                               float* __restrict__ norms,
                                               int nbn, int Ndim, int Kdim) {
  __shared__ __align__(16) __bf16 As[128 * 64];
  __shared__ __align__(16) __bf16 Bs[128 * 64];
  const int tid = threadIdx.x;
  const int wave = tid >> 6, lane = tid & 63;
  const int l15 = lane & 15, quad = lane >> 4;
  const int id = blockIdx.x;
  const int xcd = id & 7, t = id >> 3;
  const int nblk = t % nbn, mblk = (t / nbn) * 8 + xcd;
  const int m0 = mblk * 128, n0 = nblk * 128;
  const int wrow = (wave >> 1) * 64, wcol = (wave & 1) * 64;
  const int rs = lane >> 3;
  const int swz_st = ((lane & 7) ^ rs) * 8;
  const int s7 = l15 & 7;

  floatx4 zero = {0.f, 0.f, 0.f, 0.f};
  floatx4 acc[4][4];
  for (int i = 0; i < 4; ++i)
    for (int j = 0; j < 4; ++j) acc[i][j] = zero;

  for (int kt = 0; kt < Kdim; kt += 64) {
    __syncthreads();
    for (int c = 0; c < 8; ++c) {
      int g = wave * 8 + c;
      const __bf16* src;
      __bf16* dst;
      if (g < 16) {
        int row = m0 + g * 8 + rs;
        src = A + (size_t)row * Kdim + kt + swz_st;
        dst = As + g * 512;
      } else {
        int g2 = g - 16;
        int row = n0 + g2 * 8 + rs;
        src = Bt + (size_t)row * Kdim + kt + swz_st;
        dst = Bs + g2 * 512;
      }
      gload_lds16(src, dst + lane * 8);
    }
    __syncthreads();
    for (int hh = 0; hh < 2; ++hh) {
      int ko = ((hh * 4 + quad) ^ s7) * 8;
      bf16x8 a[4], b[4];
      for (int i = 0; i < 4; ++i)
        a[i] = *(const bf16x8*)(As + (wrow + i * 16 + l15) * 64 + ko);
      for (int j = 0; j < 4; ++j)
        b[j] = *(const bf16x8*)(Bs + (wcol + j * 16 + l15) * 64 + ko);
      for (int i = 0; i < 4; ++i)
        for (int j = 0; j < 4; ++j)
          acc[i][j] = __builtin_amdgcn_mfma_f32_16x16x32_bf16(a[i], b[j], acc[i][j], 0, 0, 0);
    }
  }

  // fused q/k norms for the QKV GEMM (cols 0..511 = q heads, 512..1023 = k heads)
  if (EPI == 4) {
    int head_global = (n0 + wcol) >> 6;
    int kind = head_global >> 3;          // 0=q 1=k 2=v
    if (kind < 2) {
      int h = head_global & 7;
      for (int i = 0; i < 4; ++i)
        for (int r = 0; r < 4; ++r) {
          float sq = 0.f;
          for (int j = 0; j < 4; ++j) {
            float v = acc[i][j][r];
            sq += v * v;
          }
          for (int m = 1; m < 16; m <<= 1) sq += __shfl_xor(sq, m, 64);
          if (l15 == 0) {
            int arow = m0 + wrow + i * 16 + quad * 4 + r;
            int bb = arow >> 9, ss = arow & 511;
            norms[kind * 131072 + ((bb << 3) + h) * 512 + ss] = sqrtf(sq);
          }
        }
    }
  }

  for (int i = 0; i < 4; ++i)
    for (int j = 0; j < 4; ++j) {
      int row = m0 + wrow + i * 16 + quad * 4;
      int col = n0 + wcol + j * 16 + l15;
      float bv = (EPI == 2) ? bias[col] : 0.f;
      for (int r = 0; r < 4; ++r) {
        float v = acc[i][j][r];
        size_t idx = (size_t)(row + r) * Ndim + col;
        if (EPI == 4) {
          ((__bf16*)Cv)[idx] = (__bf16)v;
        } else if (EPI == 1) {
          ((float*)Cv)[idx] = v;
        } else {  // EPI == 2
          v += bv;
          v = v > 0.f ? v : 0.f;
          ((__bf16*)Cv)[idx] = (__bf16)v;
        }
      }
    }
}

// ---------------------------------------------------------------- V transpose: qkv v-part -> Vt_g[bh][64][512]
__global__ __launch_bounds__(256) void vtrans_kernel(const __bf16* __restrict__ qkv,
                                                     __bf16* __restrict__ vtg) {
  __shared__ __align__(16) unsigned short til[64][68];
  const int tid = threadIdx.x;
  const int st = blockIdx.x;
  const int bh = blockIdx.y;
  const int b = bh >> 3, h = bh & 7;
  const unsigned short* src = (const unsigned short*)qkv +
      (size_t)(b * 512 + st * 64) * 1536 + 1024 + h * 64;
  for (int it = 0; it < 2; ++it) {
    int row = it * 32 + (tid >> 3);
    int c8 = (tid & 7) * 8;
    bf16x8 v = *(const bf16x8*)((const __bf16*)src + (size_t)row * 1536 + c8);
    for (int i = 0; i < 8; ++i) til[row][c8 + i] = ((unsigned short*)&v)[i];
  }
  __syncthreads();
  unsigned short* dst = (unsigned short*)vtg + (size_t)bh * 32768 + st * 64;
  for (int it = 0; it < 2; ++it) {
    int d = it * 32 + (tid >> 3);
    int s8 = (tid & 7) * 8;
    unsigned short v[8];
    for (int i = 0; i < 8; ++i) v[i] = til[s8 + i][d];
    *(bf16x8*)(dst + (size_t)d * 512 + s8) = *(bf16x8*)v;
  }
}

// ---------------------------------------------------------------- attention: block = (qhalf, bh)
__global__ __launch_bounds__(256) void attn_kernel(const __bf16* __restrict__ qkv,
                                                   const __bf16* __restrict__ vtg,
                                                   const float* __restrict__ norms,
                                                   __bf16* __restrict__ out) {
  __shared__ __align__(16) __bf16 Ks[64 * 64];   // [sk][d]
  __shared__ __align__(16) __bf16 Vs[64 * 64];   // [d][sk]
  __shared__ __align__(16) __bf16 P[4][16 * 72];
  const int tid = threadIdx.x, wave = tid >> 6, lane = tid & 63;
  const int l15 = lane & 15, quad = lane >> 4;
  const int qh = blockIdx.x;
  const int bh = blockIdx.y;
  const int b = bh >> 3, h = bh & 7;
  const int qbase = qh * 256 + wave * 64;
  const int rs = lane >> 3;
  const int swz_st = ((lane & 7) ^ rs) * 8;
  const int s7 = l15 & 7;

  const __bf16* Qb = qkv + (size_t)(b * 512) * 1536 + h * 64;
  const __bf16* Kb = Qb + 512;
  const __bf16* Vtb = vtg + (size_t)bh * 32768;
  const float* nkbase = norms + 131072 + bh * 512;
  __bf16* Pw = P[wave];

  bf16x8 aq[4][2];
  float nq[4][4];
  for (int ch = 0; ch < 4; ++ch) {
    int qrow = qbase + ch * 16;
    aq[ch][0] = *(const bf16x8*)(Qb + (size_t)(qrow + l15) * 1536 + quad * 8);
    aq[ch][1] = *(const bf16x8*)(Qb + (size_t)(qrow + l15) * 1536 + 32 + quad * 8);
    for (int r = 0; r < 4; ++r) nq[ch][r] = norms[bh * 512 + qrow + quad * 4 + r];
  }

  floatx4 zero = {0.f, 0.f, 0.f, 0.f};
  floatx4 o[4][4];
  float lsum[4][4];
  for (int ch = 0; ch < 4; ++ch)
    for (int jd = 0; jd < 4; ++jd) o[ch][jd] = zero;
  for (int ch = 0; ch < 4; ++ch)
    for (int r = 0; r < 4; ++r) lsum[ch][r] = 0.f;

  for (int kt = 0; kt < 8; ++kt) {
    int s0 = kt * 64;
    __syncthreads();
    for (int c = 0; c < 4; ++c) {
      int g = wave * 4 + c;
      const __bf16* src;
      __bf16* dst;
      if (g < 8) {
        int sk = g * 8 + rs;
        src = Kb + (size_t)(s0 + sk) * 1536 + swz_st;
        dst = Ks + g * 512;
      } else {
        int g2 = g - 8;
        int d = g2 * 8 + rs;
        src = Vtb + (size_t)d * 512 + s0 + swz_st;
        dst = Vs + g2 * 512;
      }
      gload_lds16(src, dst + lane * 8);
    }
    __syncthreads();

    float nk[4];
    for (int j = 0; j < 4; ++j) nk[j] = nkbase[s0 + j * 16 + l15];

    for (int ch = 0; ch < 4; ++ch) {
      floatx4 z[4];
      for (int j = 0; j < 4; ++j) {
        int r64 = (j * 16 + l15) * 64;
        bf16x8 b0 = *(const bf16x8*)(Ks + r64 + ((quad ^ s7) * 8));
        bf16x8 b1 = *(const bf16x8*)(Ks + r64 + (((4 + quad) ^ s7) * 8));
        floatx4 zz = zero;
        zz = __builtin_amdgcn_mfma_f32_16x16x32_bf16(aq[ch][0], b0, zz, 0, 0, 0);
        zz = __builtin_amdgcn_mfma_f32_16x16x32_bf16(aq[ch][1], b1, zz, 0, 0, 0);
        z[j] = zz;
      }
      for (int j = 0; j < 4; ++j)
        for (int r = 0; r < 4; ++r) {
          float den = nq[ch][r] * nk[j];
          den = den > COS_EPS ? den : COS_EPS;
          float p = __expf(z[j][r] * __builtin_amdgcn_rcpf(den) * INV_TEMP);
          lsum[ch][r] += p;
          Pw[(quad * 4 + r) * 72 + j * 16 + l15] = (__bf16)p;
        }
      bf16x8 ap0 = *(const bf16x8*)(Pw + l15 * 72 + quad * 8);
      bf16x8 ap1 = *(const bf16x8*)(Pw + l15 * 72 + 32 + quad * 8);
      for (int jd = 0; jd < 4; ++jd) {
        int r64 = (jd * 16 + l15) * 64;
        bf16x8 v0 = *(const bf16x8*)(Vs + r64 + ((quad ^ s7) * 8));
        bf16x8 v1 = *(const bf16x8*)(Vs + r64 + (((4 + quad) ^ s7) * 8));
        o[ch][jd] = __builtin_amdgcn_mfma_f32_16x16x32_bf16(ap0, v0, o[ch][jd], 0, 0, 0);
        o[ch][jd] = __builtin_amdgcn_mfma_f32_16x16x32_bf16(ap1, v1, o[ch][jd], 0, 0, 0);
      }
    }
  }

  for (int ch = 0; ch < 4; ++ch)
    for (int r = 0; r < 4; ++r) {
      float s = lsum[ch][r];
      for (int m = 1; m < 16; m <<= 1) s += __shfl_xor(s, m, 64);
      lsum[ch][r] = __builtin_amdgcn_rcpf(s);
    }
  for (int ch = 0; ch < 4; ++ch)
    for (int jd = 0; jd < 4; ++jd)
      for (int r = 0; r < 4; ++r) {
        int q = qbase + ch * 16 + quad * 4 + r;
        int d = jd * 16 + l15;
        out[(size_t)(b * 512 + q) * 512 + h * 64 + d] = (__bf16)(o[ch][jd][r] * lsum[ch][r]);
      }
}

// ---------------------------------------------------------------- residual + layernorm
// X1BF: X1 is bf16 (else f32). WF: write f32 out. WB: write bf16 out.
template <bool X1BF, bool WF, bool WB>
__global__ __launch_bounds__(256) void resid_ln(const float* __restrict__ X1f,
                                                const __bf16* __restrict__ X1b,
                                                const float* __restrict__ X2,
                                                const float* __restrict__ bias,
                                                const float* __restrict__ g,
                                                const float* __restrict__ be,
                                                float* __restrict__ outf,
                                                __bf16* __restrict__ outb) {
  int row = blockIdx.x * 4 + (threadIdx.x >> 6);
  int lane = threadIdx.x & 63;
  float v[8];
  if (X1BF) {
    bf16x8 a = *(const bf16x8*)(X1b + (size_t)row * 512 + lane * 8);
    for (int i = 0; i < 8; ++i) v[i] = (float)a[i];
    const float4* r2 = (const float4*)(X2 + (size_t)row * 512);
    float4 b0 = r2[lane * 2], b1 = r2[lane * 2 + 1];
    v[0] += b0.x; v[1] += b0.y; v[2] += b0.z; v[3] += b0.w;
    v[4] += b1.x; v[5] += b1.y; v[6] += b1.z; v[7] += b1.w;
    if (bias) {
      const float* bp = bias + lane * 8;
      for (int i = 0; i < 8; ++i) v[i] += bp[i];
    }
  } else {
    const float4* r1 = (const float4*)(X1f + (size_t)row * 512);
    const float4* r2 = (const float4*)(X2 + (size_t)row * 512);
    float4 a0 = r1[lane * 2], a1 = r1[lane * 2 + 1];
    float4 b0 = r2[lane * 2], b1 = r2[lane * 2 + 1];
    v[0] = a0.x + b0.x; v[1] = a0.y + b0.y; v[2] = a0.z + b0.z; v[3] = a0.w + b0.w;
    v[4] = a1.x + b1.x; v[5] = a1.y + b1.y; v[6] = a1.z + b1.z; v[7] = a1.w + b1.w;
  }
  float s = 0.f, sq = 0.f;
  for (int i = 0; i < 8; ++i) {
    s += v[i];
    sq += v[i] * v[i];
  }
  for (int m = 1; m < 64; m <<= 1) {
    s += __shfl_xor(s, m, 64);
    sq += __shfl_xor(sq, m, 64);
  }
  float mean = s * (1.f / 512.f);
  float var = sq * (1.f / 512.f) - mean * mean;
  float rstd = rsqrtf(var + LN_EPS);
  const float* gp = g + lane * 8;
  const float* bp2 = be + lane * 8;
  float o[8];
  for (int i = 0; i < 8; ++i) o[i] = (v[i] - mean) * rstd * gp[i] + bp2[i];
  if (WF) {
    float4 w0 = {o[0], o[1], o[2], o[3]}, w1 = {o[4], o[5], o[6], o[7]};
    ((float4*)(outf + (size_t)row * 512))[lane * 2] = w0;
    ((float4*)(outf + (size_t)row * 512))[lane * 2 + 1] = w1;
  }
  if (WB) {
    __bf16 tmp[8];
    for (int i = 0; i < 8; ++i) tmp[i] = (__bf16)o[i];
    *(bf16x8*)(outb + (size_t)row * 512 + lane * 8) = *(bf16x8*)tmp;
  }
}

// ---------------------------------------------------------------- launcher
extern "C" void kernel_launch(void* const* d_in, const int* in_sizes, int n_in,
                              void* d_out, int out_size, void* d_ws, size_t ws_size,
                              hipStream_t stream) {
  const float* x     = (const float*)d_in[0];
  const float* w_q   = (const float*)d_in[1];
  const float* w_k   = (const float*)d_in[2];
  const float* w_v   = (const float*)d_in[3];
  const float* w_o   = (const float*)d_in[4];
  const float* w_ff1 = (const float*)d_in[5];
  const float* b_ff1 = (const float*)d_in[6];
  const float* w_ff2 = (const float*)d_in[7];
  const float* b_ff2 = (const float*)d_in[8];
  const float* g1    = (const float*)d_in[9];
  const float* b1    = (const float*)d_in[10];
  const float* g2    = (const float*)d_in[11];
  const float* b2    = (const float*)d_in[12];
  float* out = (float*)d_out;

  char* ws = (char*)d_ws;
  size_t off = 0;
  auto alloc = [&](size_t bytes) -> void* {
    void* p = ws + off;
    off += (bytes + 255) & ~(size_t)255;
    return p;
  };
  __bf16* xb     = (__bf16*)alloc((size_t)Mrows * 512 * 2);
  __bf16* wt_qkv = (__bf16*)alloc((size_t)1536 * 512 * 2);
  __bf16* wt_o   = (__bf16*)alloc((size_t)512 * 512 * 2);
  __bf16* wt_ff1 = (__bf16*)alloc((size_t)2048 * 512 * 2);
  __bf16* wt_ff2 = (__bf16*)alloc((size_t)512 * 2048 * 2);
  __bf16* qkv    = (__bf16*)alloc((size_t)Mrows * 1536 * 2);
  float*  norms  = (float*)alloc((size_t)262144 * 4);
  __bf16* attn   = (__bf16*)alloc((size_t)Mrows * 512 * 2);
  float*  proj   = (float*)alloc((size_t)Mrows * 512 * 4);   // w_o out, then ffn2 out
  __bf16* h1b    = (__bf16*)alloc((size_t)Mrows * 512 * 2);
  __bf16* mid    = (__bf16*)alloc((size_t)Mrows * 2048 * 2);
  __bf16* vtg    = mid;            // alias: dead before ff1 writes mid

  prep_kernel<<<8960, 256, 0, stream>>>(x, xb, w_q, w_k, w_v, w_o, w_ff1, w_ff2,
                                        wt_qkv, wt_qkv + 512 * 512, wt_qkv + 2 * 512 * 512,
                                        wt_o, wt_ff1, wt_ff2);

  // QKV: 12 n-tiles x 128 m-tiles, fused norms
  gemm_bt<4><<<dim3(12 * 128), 256, 0, stream>>>(xb, wt_qkv, qkv, nullptr,
                                                 norms, 12, 1536, 512);
  vtrans_kernel<<<dim3(8, 256), 256, 0, stream>>>(qkv, vtg);
  attn_kernel<<<dim3(2, 256), 256, 0, stream>>>(qkv, vtg, norms, attn);
  // w_o proj -> f32
  gemm_bt<1><<<dim3(4 * 128), 256, 0, stream>>>(attn, wt_o, proj, nullptr,
                                                nullptr, 4, 512, 512);
  // LN1: x + proj -> h1b (bf16 only)
  resid_ln<false, false, true><<<4096, 256, 0, stream>>>(x, nullptr, proj, nullptr,
                                                         g1, b1, nullptr, h1b);
  // FFN1
  gemm_bt<2><<<dim3(16 * 128), 256, 0, stream>>>(h1b, wt_ff1, mid, b_ff1,
                                                 nullptr, 16, 2048, 512);
  // FFN2: single pass, K=2048
  gemm_bt<1><<<dim3(4 * 128), 256, 0, stream>>>(mid, wt_ff2, proj, nullptr,
                                                nullptr, 4, 512, 2048);
  // LN2: h1b + proj + b_ff2 -> out (f32)
  resid_ln<true, true, false><<<4096, 256, 0, stream>>>(nullptr, h1b, proj, b_ff2,
                                                        g2, b2, out, nullptr);
}

// Round 6
// 339.738 us; speedup vs baseline: 1.6176x; 1.0278x over previous
//
#include <hip/hip_runtime.h>
#include <cmath>

// ---------------------------------------------------------------- types
typedef __bf16 bf16x8 __attribute__((ext_vector_type(8)));
typedef float  floatx4 __attribute__((ext_vector_type(4)));

#define LN_EPS 1e-5f
#define COS_EPS 1e-8f
#define INV_TEMP 0.125f   // 1/sqrt(64)

// B=32 S=512 D=512 H=8 DK=DV=64 DFF=2048, M = B*S = 16384
static const int Mrows = 16384;

__device__ __forceinline__ void gload_lds16(const void* g, void* l) {
  __builtin_amdgcn_global_load_lds(
      (const __attribute__((address_space(1))) void*)g,
      (__attribute__((address_space(3))) void*)l, 16, 0, 0);
}

// ---------------------------------------------------------------- fused prep: x->bf16 + 6 weight transposes
__global__ __launch_bounds__(256) void prep_kernel(const float* __restrict__ x, __bf16* __restrict__ xb,
                                                   const float* __restrict__ wq, const float* __restrict__ wk,
                                                   const float* __restrict__ wv, const float* __restrict__ wo,
                                                   const float* __restrict__ wff1, const float* __restrict__ wff2,
                                                   __bf16* __restrict__ tq, __bf16* __restrict__ tk,
                                                   __bf16* __restrict__ tv, __bf16* __restrict__ to_,
                                                   __bf16* __restrict__ tff1, __bf16* __restrict__ tff2) {
  const int bid = blockIdx.x, tid = threadIdx.x;
  if (bid < 8192) {
    int i = bid * 256 + tid;
    float4 v = ((const float4*)x)[i];
    __bf16* d = xb + i * 4;
    d[0] = (__bf16)v.x; d[1] = (__bf16)v.y; d[2] = (__bf16)v.z; d[3] = (__bf16)v.w;
    return;
  }
  __shared__ __bf16 til[64][72];
  int t = bid - 8192;
  const float* src; __bf16* dst; int R, C, bx, by;
  if (t < 256) {
    int w = t >> 6, tt = t & 63;
    const float* srcs[4] = {wq, wk, wv, wo};
    __bf16* dsts[4] = {tq, tk, tv, to_};
    src = srcs[w]; dst = dsts[w]; R = 512; C = 512; bx = tt & 7; by = tt >> 3;
  } else if (t < 512) {
    int tt = t - 256;
    src = wff1; dst = tff1; R = 512; C = 2048; bx = tt & 31; by = tt >> 5;
  } else {
    int tt = t - 512;
    src = wff2; dst = tff2; R = 2048; C = 512; bx = tt & 7; by = tt >> 3;
  }
  const float* s = src + (size_t)(by * 64) * C + bx * 64;
  int r = tid >> 4, c4 = (tid & 15) * 4;
  for (int p = 0; p < 4; ++p) {
    int rr = r + p * 16;
    float4 v = *(const float4*)(s + (size_t)rr * C + c4);
    til[c4 + 0][rr] = (__bf16)v.x;
    til[c4 + 1][rr] = (__bf16)v.y;
    til[c4 + 2][rr] = (__bf16)v.z;
    til[c4 + 3][rr] = (__bf16)v.w;
  }
  __syncthreads();
  __bf16* d = dst + (size_t)(bx * 64) * R + by * 64;
  int orow = tid >> 3, oc8 = (tid & 7) * 8;
  for (int p = 0; p < 2; ++p) {
    int rr = orow + p * 32;
    *(bf16x8*)(d + (size_t)rr * R + oc8) = *(const bf16x8*)(&til[rr][oc8]);
  }
}

// ---------------------------------------------------------------- GEMM  C = A[M,K] * Bt[N,K]^T -> bf16
// BK=64, 128B LDS rows, 16B-slot XOR swizzle -> conflict-free b128 reads.
// Epilogue routes acc through padded LDS tile -> global_store_dwordx4.
// EPI: 0 plain, 2 +bias,relu, 4 plain + fused q/k norms
template <int EPI>
__global__ __launch_bounds__(256) void gemm_bt(const __bf16* __restrict__ A,
                                               const __bf16* __restrict__ Bt,
                                               __bf16* __restrict__ Cv,
                                               const float* __restrict__ bias,
                                               float* __restrict__ norms,
                                               int nbn, int Ndim, int Kdim) {
  __shared__ __align__(16) char smem[128 * 144 * 2];   // 36 KB: K-loop uses 32 KB as As/Bs
  __bf16* As = (__bf16*)smem;
  __bf16* Bs = (__bf16*)(smem + 32768 / 2);
  const int tid = threadIdx.x;
  const int wave = tid >> 6, lane = tid & 63;
  const int l15 = lane & 15, quad = lane >> 4;
  const int id = blockIdx.x;
  const int xcd = id & 7, t = id >> 3;
  const int nblk = t % nbn, mblk = (t / nbn) * 8 + xcd;
  const int m0 = mblk * 128, n0 = nblk * 128;
  const int wrow = (wave >> 1) * 64, wcol = (wave & 1) * 64;
  const int rs = lane >> 3;
  const int swz_st = ((lane & 7) ^ rs) * 8;
  const int s7 = l15 & 7;

  floatx4 zero = {0.f, 0.f, 0.f, 0.f};
  floatx4 acc[4][4];
  for (int i = 0; i < 4; ++i)
    for (int j = 0; j < 4; ++j) acc[i][j] = zero;

  for (int kt = 0; kt < Kdim; kt += 64) {
    __syncthreads();
    for (int c = 0; c < 8; ++c) {
      int g = wave * 8 + c;
      const __bf16* src;
      __bf16* dst;
      if (g < 16) {
        int row = m0 + g * 8 + rs;
        src = A + (size_t)row * Kdim + kt + swz_st;
        dst = As + g * 512;
      } else {
        int g2 = g - 16;
        int row = n0 + g2 * 8 + rs;
        src = Bt + (size_t)row * Kdim + kt + swz_st;
        dst = Bs + g2 * 512;
      }
      gload_lds16(src, dst + lane * 8);
    }
    __syncthreads();
    for (int hh = 0; hh < 2; ++hh) {
      int ko = ((hh * 4 + quad) ^ s7) * 8;
      bf16x8 a[4], b[4];
      for (int i = 0; i < 4; ++i)
        a[i] = *(const bf16x8*)(As + (wrow + i * 16 + l15) * 64 + ko);
      for (int j = 0; j < 4; ++j)
        b[j] = *(const bf16x8*)(Bs + (wcol + j * 16 + l15) * 64 + ko);
      for (int i = 0; i < 4; ++i)
        for (int j = 0; j < 4; ++j)
          acc[i][j] = __builtin_amdgcn_mfma_f32_16x16x32_bf16(a[i], b[j], acc[i][j], 0, 0, 0);
    }
  }

  // fused q/k norms (QKV GEMM; cols 0..511 = q heads, 512..1023 = k heads)
  if (EPI == 4) {
    int head_global = (n0 + wcol) >> 6;
    int kind = head_global >> 3;          // 0=q 1=k 2=v
    if (kind < 2) {
      int h = head_global & 7;
      for (int i = 0; i < 4; ++i)
        for (int r = 0; r < 4; ++r) {
          float sq = 0.f;
          for (int j = 0; j < 4; ++j) {
            float v = acc[i][j][r];
            sq += v * v;
          }
          for (int m = 1; m < 16; m <<= 1) sq += __shfl_xor(sq, m, 64);
          if (l15 == 0) {
            int arow = m0 + wrow + i * 16 + quad * 4 + r;
            int bb = arow >> 9, ss = arow & 511;
            norms[kind * 131072 + ((bb << 3) + h) * 512 + ss] = sqrtf(sq);
          }
        }
    }
  }

  // epilogue: acc -> padded LDS tile -> wide stores
  __syncthreads();                      // all As/Bs reads done before reuse
  __bf16* Cs = (__bf16*)smem;           // [128][144]
  for (int i = 0; i < 4; ++i)
    for (int j = 0; j < 4; ++j) {
      int coll = wcol + j * 16 + l15;
      float bv = (EPI == 2) ? bias[n0 + coll] : 0.f;
      for (int r = 0; r < 4; ++r) {
        float v = acc[i][j][r];
        if (EPI == 2) {
          v += bv;
          v = v > 0.f ? v : 0.f;
        }
        Cs[(wrow + i * 16 + quad * 4 + r) * 144 + coll] = (__bf16)v;
      }
    }
  __syncthreads();
  for (int p = 0; p < 8; ++p) {
    int row = p * 16 + (tid >> 4);
    int c8 = (tid & 15) * 8;
    *(bf16x8*)(Cv + (size_t)(m0 + row) * Ndim + n0 + c8) =
        *(const bf16x8*)(Cs + row * 144 + c8);
  }
}

// ---------------------------------------------------------------- V transpose: qkv v-part -> Vt_g[bh][64][512]
__global__ __launch_bounds__(256) void vtrans_kernel(const __bf16* __restrict__ qkv,
                                                     __bf16* __restrict__ vtg) {
  __shared__ __align__(16) unsigned short til[64][68];
  const int tid = threadIdx.x;
  const int st = blockIdx.x;
  const int bh = blockIdx.y;
  const int b = bh >> 3, h = bh & 7;
  const unsigned short* src = (const unsigned short*)qkv +
      (size_t)(b * 512 + st * 64) * 1536 + 1024 + h * 64;
  for (int it = 0; it < 2; ++it) {
    int row = it * 32 + (tid >> 3);
    int c8 = (tid & 7) * 8;
    bf16x8 v = *(const bf16x8*)((const __bf16*)src + (size_t)row * 1536 + c8);
    for (int i = 0; i < 8; ++i) til[row][c8 + i] = ((unsigned short*)&v)[i];
  }
  __syncthreads();
  unsigned short* dst = (unsigned short*)vtg + (size_t)bh * 32768 + st * 64;
  for (int it = 0; it < 2; ++it) {
    int d = it * 32 + (tid >> 3);
    int s8 = (tid & 7) * 8;
    unsigned short v[8];
    for (int i = 0; i < 8; ++i) v[i] = til[s8 + i][d];
    *(bf16x8*)(dst + (size_t)d * 512 + s8) = *(bf16x8*)v;
  }
}

// ---------------------------------------------------------------- attention: 1-D grid, bh=id&255, qh=id>>8
// (pairs the two q-half blocks of a head 256 ids apart -> same XCD -> K/V L2 reuse)
__global__ __launch_bounds__(256) void attn_kernel(const __bf16* __restrict__ qkv,
                                                   const __bf16* __restrict__ vtg,
                                                   const float* __restrict__ norms,
                                                   __bf16* __restrict__ out) {
  __shared__ __align__(16) __bf16 Ks[64 * 64];   // [sk][d]
  __shared__ __align__(16) __bf16 Vs[64 * 64];   // [d][sk]
  __shared__ __align__(16) __bf16 P[4][16 * 72];
  const int tid = threadIdx.x, wave = tid >> 6, lane = tid & 63;
  const int l15 = lane & 15, quad = lane >> 4;
  const int bh = blockIdx.x & 255;
  const int qh = blockIdx.x >> 8;
  const int b = bh >> 3, h = bh & 7;
  const int qbase = qh * 256 + wave * 64;
  const int rs = lane >> 3;
  const int swz_st = ((lane & 7) ^ rs) * 8;
  const int s7 = l15 & 7;

  const __bf16* Qb = qkv + (size_t)(b * 512) * 1536 + h * 64;
  const __bf16* Kb = Qb + 512;
  const __bf16* Vtb = vtg + (size_t)bh * 32768;
  const float* nkbase = norms + 131072 + bh * 512;
  __bf16* Pw = P[wave];

  bf16x8 aq[4][2];
  float nq[4][4];
  for (int ch = 0; ch < 4; ++ch) {
    int qrow = qbase + ch * 16;
    aq[ch][0] = *(const bf16x8*)(Qb + (size_t)(qrow + l15) * 1536 + quad * 8);
    aq[ch][1] = *(const bf16x8*)(Qb + (size_t)(qrow + l15) * 1536 + 32 + quad * 8);
    for (int r = 0; r < 4; ++r) nq[ch][r] = norms[bh * 512 + qrow + quad * 4 + r];
  }

  floatx4 zero = {0.f, 0.f, 0.f, 0.f};
  floatx4 o[4][4];
  float lsum[4][4];
  for (int ch = 0; ch < 4; ++ch)
    for (int jd = 0; jd < 4; ++jd) o[ch][jd] = zero;
  for (int ch = 0; ch < 4; ++ch)
    for (int r = 0; r < 4; ++r) lsum[ch][r] = 0.f;

  for (int kt = 0; kt < 8; ++kt) {
    int s0 = kt * 64;
    __syncthreads();
    for (int c = 0; c < 4; ++c) {
      int g = wave * 4 + c;
      const __bf16* src;
      __bf16* dst;
      if (g < 8) {
        int sk = g * 8 + rs;
        src = Kb + (size_t)(s0 + sk) * 1536 + swz_st;
        dst = Ks + g * 512;
      } else {
        int g2 = g - 8;
        int d = g2 * 8 + rs;
        src = Vtb + (size_t)d * 512 + s0 + swz_st;
        dst = Vs + g2 * 512;
      }
      gload_lds16(src, dst + lane * 8);
    }
    __syncthreads();

    float nk[4];
    for (int j = 0; j < 4; ++j) nk[j] = nkbase[s0 + j * 16 + l15];

    for (int ch = 0; ch < 4; ++ch) {
      floatx4 z[4];
      for (int j = 0; j < 4; ++j) {
        int r64 = (j * 16 + l15) * 64;
        bf16x8 b0 = *(const bf16x8*)(Ks + r64 + ((quad ^ s7) * 8));
        bf16x8 b1 = *(const bf16x8*)(Ks + r64 + (((4 + quad) ^ s7) * 8));
        floatx4 zz = zero;
        zz = __builtin_amdgcn_mfma_f32_16x16x32_bf16(aq[ch][0], b0, zz, 0, 0, 0);
        zz = __builtin_amdgcn_mfma_f32_16x16x32_bf16(aq[ch][1], b1, zz, 0, 0, 0);
        z[j] = zz;
      }
      for (int j = 0; j < 4; ++j)
        for (int r = 0; r < 4; ++r) {
          float den = nq[ch][r] * nk[j];
          den = den > COS_EPS ? den : COS_EPS;
          float p = __expf(z[j][r] * __builtin_amdgcn_rcpf(den) * INV_TEMP);
          lsum[ch][r] += p;
          Pw[(quad * 4 + r) * 72 + j * 16 + l15] = (__bf16)p;
        }
      bf16x8 ap0 = *(const bf16x8*)(Pw + l15 * 72 + quad * 8);
      bf16x8 ap1 = *(const bf16x8*)(Pw + l15 * 72 + 32 + quad * 8);
      for (int jd = 0; jd < 4; ++jd) {
        int r64 = (jd * 16 + l15) * 64;
        bf16x8 v0 = *(const bf16x8*)(Vs + r64 + ((quad ^ s7) * 8));
        bf16x8 v1 = *(const bf16x8*)(Vs + r64 + (((4 + quad) ^ s7) * 8));
        o[ch][jd] = __builtin_amdgcn_mfma_f32_16x16x32_bf16(ap0, v0, o[ch][jd], 0, 0, 0);
        o[ch][jd] = __builtin_amdgcn_mfma_f32_16x16x32_bf16(ap1, v1, o[ch][jd], 0, 0, 0);
      }
    }
  }

  for (int ch = 0; ch < 4; ++ch)
    for (int r = 0; r < 4; ++r) {
      float s = lsum[ch][r];
      for (int m = 1; m < 16; m <<= 1) s += __shfl_xor(s, m, 64);
      lsum[ch][r] = __builtin_amdgcn_rcpf(s);
    }
  for (int ch = 0; ch < 4; ++ch)
    for (int jd = 0; jd < 4; ++jd)
      for (int r = 0; r < 4; ++r) {
        int q = qbase + ch * 16 + quad * 4 + r;
        int d = jd * 16 + l15;
        out[(size_t)(b * 512 + q) * 512 + h * 64 + d] = (__bf16)(o[ch][jd][r] * lsum[ch][r]);
      }
}

// ---------------------------------------------------------------- residual + layernorm
// X1BF: X1 is bf16 (else f32). X2 always bf16. WF: f32 out. WB: bf16 out.
template <bool X1BF, bool WF, bool WB>
__global__ __launch_bounds__(256) void resid_ln(const float* __restrict__ X1f,
                                                const __bf16* __restrict__ X1b,
                                                const __bf16* __restrict__ X2,
                                                const float* __restrict__ bias,
                                                const float* __restrict__ g,
                                                const float* __restrict__ be,
                                                float* __restrict__ outf,
                                                __bf16* __restrict__ outb) {
  int row = blockIdx.x * 4 + (threadIdx.x >> 6);
  int lane = threadIdx.x & 63;
  float v[8];
  bf16x8 b8 = *(const bf16x8*)(X2 + (size_t)row * 512 + lane * 8);
  if (X1BF) {
    bf16x8 a = *(const bf16x8*)(X1b + (size_t)row * 512 + lane * 8);
    for (int i = 0; i < 8; ++i) v[i] = (float)a[i] + (float)b8[i];
  } else {
    const float4* r1 = (const float4*)(X1f + (size_t)row * 512);
    float4 a0 = r1[lane * 2], a1 = r1[lane * 2 + 1];
    v[0] = a0.x; v[1] = a0.y; v[2] = a0.z; v[3] = a0.w;
    v[4] = a1.x; v[5] = a1.y; v[6] = a1.z; v[7] = a1.w;
    for (int i = 0; i < 8; ++i) v[i] += (float)b8[i];
  }
  if (bias) {
    const float* bp = bias + lane * 8;
    for (int i = 0; i < 8; ++i) v[i] += bp[i];
  }
  float s = 0.f, sq = 0.f;
  for (int i = 0; i < 8; ++i) {
    s += v[i];
    sq += v[i] * v[i];
  }
  for (int m = 1; m < 64; m <<= 1) {
    s += __shfl_xor(s, m, 64);
    sq += __shfl_xor(sq, m, 64);
  }
  float mean = s * (1.f / 512.f);
  float var = sq * (1.f / 512.f) - mean * mean;
  float rstd = rsqrtf(var + LN_EPS);
  const float* gp = g + lane * 8;
  const float* bp2 = be + lane * 8;
  float o[8];
  for (int i = 0; i < 8; ++i) o[i] = (v[i] - mean) * rstd * gp[i] + bp2[i];
  if (WF) {
    float4 w0 = {o[0], o[1], o[2], o[3]}, w1 = {o[4], o[5], o[6], o[7]};
    ((float4*)(outf + (size_t)row * 512))[lane * 2] = w0;
    ((float4*)(outf + (size_t)row * 512))[lane * 2 + 1] = w1;
  }
  if (WB) {
    __bf16 tmp[8];
    for (int i = 0; i < 8; ++i) tmp[i] = (__bf16)o[i];
    *(bf16x8*)(outb + (size_t)row * 512 + lane * 8) = *(bf16x8*)tmp;
  }
}

// ---------------------------------------------------------------- launcher
extern "C" void kernel_launch(void* const* d_in, const int* in_sizes, int n_in,
                              void* d_out, int out_size, void* d_ws, size_t ws_size,
                              hipStream_t stream) {
  const float* x     = (const float*)d_in[0];
  const float* w_q   = (const float*)d_in[1];
  const float* w_k   = (const float*)d_in[2];
  const float* w_v   = (const float*)d_in[3];
  const float* w_o   = (const float*)d_in[4];
  const float* w_ff1 = (const float*)d_in[5];
  const float* b_ff1 = (const float*)d_in[6];
  const float* w_ff2 = (const float*)d_in[7];
  const float* b_ff2 = (const float*)d_in[8];
  const float* g1    = (const float*)d_in[9];
  const float* b1    = (const float*)d_in[10];
  const float* g2    = (const float*)d_in[11];
  const float* b2    = (const float*)d_in[12];
  float* out = (float*)d_out;

  char* ws = (char*)d_ws;
  size_t off = 0;
  auto alloc = [&](size_t bytes) -> void* {
    void* p = ws + off;
    off += (bytes + 255) & ~(size_t)255;
    return p;
  };
  __bf16* xb     = (__bf16*)alloc((size_t)Mrows * 512 * 2);
  __bf16* wt_qkv = (__bf16*)alloc((size_t)1536 * 512 * 2);
  __bf16* wt_o   = (__bf16*)alloc((size_t)512 * 512 * 2);
  __bf16* wt_ff1 = (__bf16*)alloc((size_t)2048 * 512 * 2);
  __bf16* wt_ff2 = (__bf16*)alloc((size_t)512 * 2048 * 2);
  __bf16* qkv    = (__bf16*)alloc((size_t)Mrows * 1536 * 2);
  float*  norms  = (float*)alloc((size_t)262144 * 4);
  __bf16* attn   = (__bf16*)alloc((size_t)Mrows * 512 * 2);
  __bf16* projb  = (__bf16*)alloc((size_t)Mrows * 512 * 2);   // w_o out (bf16)
  __bf16* h1b    = (__bf16*)alloc((size_t)Mrows * 512 * 2);
  __bf16* mid    = (__bf16*)alloc((size_t)Mrows * 2048 * 2);
  __bf16* vtg    = mid;            // alias: dead before ff1 writes mid
  __bf16* f2o    = attn;           // alias: attn dead after w_o GEMM

  prep_kernel<<<8960, 256, 0, stream>>>(x, xb, w_q, w_k, w_v, w_o, w_ff1, w_ff2,
                                        wt_qkv, wt_qkv + 512 * 512, wt_qkv + 2 * 512 * 512,
                                        wt_o, wt_ff1, wt_ff2);

  // QKV: 12 n-tiles x 128 m-tiles, fused norms
  gemm_bt<4><<<dim3(12 * 128), 256, 0, stream>>>(xb, wt_qkv, qkv, nullptr,
                                                 norms, 12, 1536, 512);
  vtrans_kernel<<<dim3(8, 256), 256, 0, stream>>>(qkv, vtg);
  attn_kernel<<<dim3(512), 256, 0, stream>>>(qkv, vtg, norms, attn);
  // w_o proj -> bf16
  gemm_bt<0><<<dim3(4 * 128), 256, 0, stream>>>(attn, wt_o, projb, nullptr,
                                                nullptr, 4, 512, 512);
  // LN1: x + projb -> h1b (bf16)
  resid_ln<false, false, true><<<4096, 256, 0, stream>>>(x, nullptr, projb, nullptr,
                                                         g1, b1, nullptr, h1b);
  // FFN1 (+bias, relu)
  gemm_bt<2><<<dim3(16 * 128), 256, 0, stream>>>(h1b, wt_ff1, mid, b_ff1,
                                                 nullptr, 16, 2048, 512);
  // FFN2 -> bf16 (bias folded into LN2)
  gemm_bt<0><<<dim3(4 * 128), 256, 0, stream>>>(mid, wt_ff2, f2o, nullptr,
                                                nullptr, 4, 512, 2048);
  // LN2: h1b + f2o + b_ff2 -> out (f32)
  resid_ln<true, true, false><<<4096, 256, 0, stream>>>(nullptr, h1b, f2o, b_ff2,
                                                        g2, b2, out, nullptr);
}

// Round 7
// 328.181 us; speedup vs baseline: 1.6745x; 1.0352x over previous
//
#include <hip/hip_runtime.h>
#include <cmath>

// ---------------------------------------------------------------- types
typedef __bf16 bf16x8 __attribute__((ext_vector_type(8)));
typedef __bf16 bf16x4 __attribute__((ext_vector_type(4)));
typedef float  floatx4 __attribute__((ext_vector_type(4)));

#define LN_EPS 1e-5f
#define INV_TEMP 0.125f   // 1/sqrt(64)

// B=32 S=512 D=512 H=8 DK=DV=64 DFF=2048, M = B*S = 16384
static const int Mrows = 16384;

__device__ __forceinline__ void gload_lds16(const void* g, void* l) {
  __builtin_amdgcn_global_load_lds(
      (const __attribute__((address_space(1))) void*)g,
      (__attribute__((address_space(3))) void*)l, 16, 0, 0);
}

// ---------------------------------------------------------------- fused prep: x->bf16 + 6 weight transposes
__global__ __launch_bounds__(256) void prep_kernel(const float* __restrict__ x, __bf16* __restrict__ xb,
                                                   const float* __restrict__ wq, const float* __restrict__ wk,
                                                   const float* __restrict__ wv, const float* __restrict__ wo,
                                                   const float* __restrict__ wff1, const float* __restrict__ wff2,
                                                   __bf16* __restrict__ tq, __bf16* __restrict__ tk,
                                                   __bf16* __restrict__ tv, __bf16* __restrict__ to_,
                                                   __bf16* __restrict__ tff1, __bf16* __restrict__ tff2) {
  const int bid = blockIdx.x, tid = threadIdx.x;
  if (bid < 8192) {
    int i = bid * 256 + tid;
    float4 v = ((const float4*)x)[i];
    __bf16* d = xb + i * 4;
    d[0] = (__bf16)v.x; d[1] = (__bf16)v.y; d[2] = (__bf16)v.z; d[3] = (__bf16)v.w;
    return;
  }
  __shared__ __bf16 til[64][72];
  int t = bid - 8192;
  const float* src; __bf16* dst; int R, C, bx, by;
  if (t < 256) {
    int w = t >> 6, tt = t & 63;
    const float* srcs[4] = {wq, wk, wv, wo};
    __bf16* dsts[4] = {tq, tk, tv, to_};
    src = srcs[w]; dst = dsts[w]; R = 512; C = 512; bx = tt & 7; by = tt >> 3;
  } else if (t < 512) {
    int tt = t - 256;
    src = wff1; dst = tff1; R = 512; C = 2048; bx = tt & 31; by = tt >> 5;
  } else {
    int tt = t - 512;
    src = wff2; dst = tff2; R = 2048; C = 512; bx = tt & 7; by = tt >> 3;
  }
  const float* s = src + (size_t)(by * 64) * C + bx * 64;
  int r = tid >> 4, c4 = (tid & 15) * 4;
  for (int p = 0; p < 4; ++p) {
    int rr = r + p * 16;
    float4 v = *(const float4*)(s + (size_t)rr * C + c4);
    til[c4 + 0][rr] = (__bf16)v.x;
    til[c4 + 1][rr] = (__bf16)v.y;
    til[c4 + 2][rr] = (__bf16)v.z;
    til[c4 + 3][rr] = (__bf16)v.w;
  }
  __syncthreads();
  __bf16* d = dst + (size_t)(bx * 64) * R + by * 64;
  int orow = tid >> 3, oc8 = (tid & 7) * 8;
  for (int p = 0; p < 2; ++p) {
    int rr = orow + p * 32;
    *(bf16x8*)(d + (size_t)rr * R + oc8) = *(const bf16x8*)(&til[rr][oc8]);
  }
}

// ---------------------------------------------------------------- GEMM  C = A[M,K] * Bt[N,K]^T -> bf16
// Compile-time dims. BK=64, 128B LDS rows, 16B-slot XOR swizzle.
// EPI: 0 plain, 2 +bias,relu, 4 QKV (fused inverse q/k norms + V-transpose into vtg)
template <int EPI, int NBN, int NDIM, int KDIM>
__global__ __launch_bounds__(256) void gemm_bt(const __bf16* __restrict__ A,
                                               const __bf16* __restrict__ Bt,
                                               __bf16* __restrict__ Cv,
                                               const float* __restrict__ bias,
                                               float* __restrict__ norms,
                                               __bf16* __restrict__ vtg) {
  __shared__ __align__(16) char smem[128 * 144 * 2];   // 36 KB; K-loop uses first 32 KB
  __bf16* As = (__bf16*)smem;
  __bf16* Bs = (__bf16*)(smem + 16384);
  const int tid = threadIdx.x;
  const int wave = tid >> 6, lane = tid & 63;
  const int l15 = lane & 15, quad = lane >> 4;
  const int id = blockIdx.x;
  const int xcd = id & 7, t = id >> 3;
  const int nblk = t % NBN, mblk = (t / NBN) * 8 + xcd;
  const int m0 = mblk * 128, n0 = nblk * 128;
  const int wrow = (wave >> 1) * 64, wcol = (wave & 1) * 64;
  const int rs = lane >> 3;
  const int swz_st = ((lane & 7) ^ rs) * 8;
  const int s7 = l15 & 7;

  floatx4 zero = {0.f, 0.f, 0.f, 0.f};
  floatx4 acc[4][4];
  for (int i = 0; i < 4; ++i)
    for (int j = 0; j < 4; ++j) acc[i][j] = zero;

  for (int kt = 0; kt < KDIM; kt += 64) {
    __syncthreads();
    for (int c = 0; c < 8; ++c) {
      int g = wave * 8 + c;
      const __bf16* src;
      __bf16* dst;
      if (g < 16) {
        int row = m0 + g * 8 + rs;
        src = A + (size_t)row * KDIM + kt + swz_st;
        dst = As + g * 512;
      } else {
        int g2 = g - 16;
        int row = n0 + g2 * 8 + rs;
        src = Bt + (size_t)row * KDIM + kt + swz_st;
        dst = Bs + g2 * 512;
      }
      gload_lds16(src, dst + lane * 8);
    }
    __syncthreads();
    for (int hh = 0; hh < 2; ++hh) {
      int ko = ((hh * 4 + quad) ^ s7) * 8;
      bf16x8 a[4], b[4];
      for (int i = 0; i < 4; ++i)
        a[i] = *(const bf16x8*)(As + (wrow + i * 16 + l15) * 64 + ko);
      for (int j = 0; j < 4; ++j)
        b[j] = *(const bf16x8*)(Bs + (wcol + j * 16 + l15) * 64 + ko);
      for (int i = 0; i < 4; ++i)
        for (int j = 0; j < 4; ++j)
          acc[i][j] = __builtin_amdgcn_mfma_f32_16x16x32_bf16(a[i], b[j], acc[i][j], 0, 0, 0);
    }
  }

  if (EPI == 4) {
    int head_global = (n0 + wcol) >> 6;
    int kind = head_global >> 3;          // 0=q 1=k 2=v
    if (kind < 2) {
      // fused INVERSE q/k norms
      int h = head_global & 7;
      for (int i = 0; i < 4; ++i)
        for (int r = 0; r < 4; ++r) {
          float sq = 0.f;
          for (int j = 0; j < 4; ++j) {
            float v = acc[i][j][r];
            sq += v * v;
          }
          for (int m = 1; m < 16; m <<= 1) sq += __shfl_xor(sq, m, 64);
          if (l15 == 0) {
            int arow = m0 + wrow + i * 16 + quad * 4 + r;
            int bb = arow >> 9, ss = arow & 511;
            norms[kind * 131072 + ((bb << 3) + h) * 512 + ss] = rsqrtf(sq);
          }
        }
    } else {
      // v-tile: transpose through LDS straight into vtg[bh][d][s]
      __syncthreads();
      __bf16* Ct = (__bf16*)smem;   // [128 cols][136]
      for (int i = 0; i < 4; ++i)
        for (int j = 0; j < 4; ++j) {
          bf16x4 pk;
          for (int r = 0; r < 4; ++r) pk[r] = (__bf16)acc[i][j][r];
          *(bf16x4*)(Ct + (wcol + j * 16 + l15) * 136 + wrow + i * 16 + quad * 4) = pk;
        }
      __syncthreads();
      int b = mblk >> 2, s0r = (mblk & 3) * 128;
      for (int p = 0; p < 8; ++p) {
        int row = p * 16 + (tid >> 4);    // local d-col
        int c8 = (tid & 15) * 8;          // s-offset
        int colg = n0 + row;
        int h = (colg >> 6) & 7, d = colg & 63;
        *(bf16x8*)(vtg + ((size_t)(((b << 3) + h) * 64 + d)) * 512 + s0r + c8) =
            *(const bf16x8*)(Ct + row * 136 + c8);
      }
      return;
    }
  }

  // normal epilogue: acc -> padded LDS tile -> wide stores
  __syncthreads();
  __bf16* Cs = (__bf16*)smem;           // [128][144]
  for (int i = 0; i < 4; ++i)
    for (int j = 0; j < 4; ++j) {
      int coll = wcol + j * 16 + l15;
      float bv = (EPI == 2) ? bias[n0 + coll] : 0.f;
      for (int r = 0; r < 4; ++r) {
        float v = acc[i][j][r];
        if (EPI == 2) {
          v += bv;
          v = v > 0.f ? v : 0.f;
        }
        Cs[(wrow + i * 16 + quad * 4 + r) * 144 + coll] = (__bf16)v;
      }
    }
  __syncthreads();
  for (int p = 0; p < 8; ++p) {
    int row = p * 16 + (tid >> 4);
    int c8 = (tid & 15) * 8;
    *(bf16x8*)(Cv + (size_t)(m0 + row) * NDIM + n0 + c8) =
        *(const bf16x8*)(Cs + row * 144 + c8);
  }
}

// ---------------------------------------------------------------- attention
// grid 1024: bh = id&255, qq = id>>8 (same-XCD head pairing). Wave: 32 q-rows (2 chunks).
// S^T = mfma(K,Q): lane owns q=l15 column -> shuffle-free softmax, b64 P-writes.
// O^T = mfma(V,P): lane q=l15 matches lsum; b64 out-stores.
__global__ __launch_bounds__(256) void attn_kernel(const __bf16* __restrict__ qkv,
                                                   const __bf16* __restrict__ vtg,
                                                   const float* __restrict__ norms,
                                                   __bf16* __restrict__ out) {
  __shared__ __align__(16) __bf16 Ks[64 * 64];   // [sk][d]
  __shared__ __align__(16) __bf16 Vs[64 * 64];   // [d][sk]
  __shared__ __align__(16) __bf16 P2[4][16 * 72];
  const int tid = threadIdx.x, wave = tid >> 6, lane = tid & 63;
  const int l15 = lane & 15, quad = lane >> 4;
  const int bh = blockIdx.x & 255;
  const int qq = blockIdx.x >> 8;
  const int b = bh >> 3, h = bh & 7;
  const int qbase = qq * 128 + wave * 32;
  const int rs = lane >> 3;
  const int swz_st = ((lane & 7) ^ rs) * 8;
  const int s7 = l15 & 7;

  const __bf16* Qb = qkv + (size_t)(b * 512) * 1536 + h * 64;
  const __bf16* Kb = Qb + 512;
  const __bf16* Vtb = vtg + (size_t)bh * 32768;
  const float* nkinv = norms + 131072 + bh * 512;
  const float* nqinv = norms + bh * 512;
  __bf16* Pw = P2[wave];

  bf16x8 aq[2][2];
  float cq[2];
  for (int ch = 0; ch < 2; ++ch) {
    int qrow = qbase + ch * 16;
    aq[ch][0] = *(const bf16x8*)(Qb + (size_t)(qrow + l15) * 1536 + quad * 8);
    aq[ch][1] = *(const bf16x8*)(Qb + (size_t)(qrow + l15) * 1536 + 32 + quad * 8);
    cq[ch] = nqinv[qrow + l15] * INV_TEMP;
  }

  floatx4 zero = {0.f, 0.f, 0.f, 0.f};
  floatx4 o[2][4];
  float lsum[2] = {0.f, 0.f};
  for (int ch = 0; ch < 2; ++ch)
    for (int jd = 0; jd < 4; ++jd) o[ch][jd] = zero;

  for (int kt = 0; kt < 8; ++kt) {
    int s0 = kt * 64;
    __syncthreads();
    for (int c = 0; c < 4; ++c) {
      int g = wave * 4 + c;
      const __bf16* src;
      __bf16* dst;
      if (g < 8) {
        int sk = g * 8 + rs;
        src = Kb + (size_t)(s0 + sk) * 1536 + swz_st;
        dst = Ks + g * 512;
      } else {
        int g2 = g - 8;
        int d = g2 * 8 + rs;
        src = Vtb + (size_t)d * 512 + s0 + swz_st;
        dst = Vs + g2 * 512;
      }
      gload_lds16(src, dst + lane * 8);
    }
    __syncthreads();

    for (int ch = 0; ch < 2; ++ch) {
      // S^T: 64 sk x 16 q ; lane -> (sk = j*16+quad*4+r, q = l15)
      floatx4 z[4];
      for (int j = 0; j < 4; ++j) {
        int r64 = (j * 16 + l15) * 64;
        bf16x8 k0 = *(const bf16x8*)(Ks + r64 + ((quad ^ s7) * 8));
        bf16x8 k1 = *(const bf16x8*)(Ks + r64 + (((4 + quad) ^ s7) * 8));
        floatx4 zz = zero;
        zz = __builtin_amdgcn_mfma_f32_16x16x32_bf16(k0, aq[ch][0], zz, 0, 0, 0);
        zz = __builtin_amdgcn_mfma_f32_16x16x32_bf16(k1, aq[ch][1], zz, 0, 0, 0);
        z[j] = zz;
      }
      for (int j = 0; j < 4; ++j) {
        floatx4 nk4 = *(const floatx4*)(nkinv + s0 + j * 16 + quad * 4);
        bf16x4 pk;
        for (int r = 0; r < 4; ++r) {
          float p = __expf(z[j][r] * cq[ch] * nk4[r]);
          lsum[ch] += p;
          pk[r] = (__bf16)p;
        }
        *(bf16x4*)(Pw + l15 * 72 + j * 16 + quad * 4) = pk;
      }
      bf16x8 ap0 = *(const bf16x8*)(Pw + l15 * 72 + quad * 8);
      bf16x8 ap1 = *(const bf16x8*)(Pw + l15 * 72 + 32 + quad * 8);
      for (int jd = 0; jd < 4; ++jd) {
        int r64 = (jd * 16 + l15) * 64;
        bf16x8 v0 = *(const bf16x8*)(Vs + r64 + ((quad ^ s7) * 8));
        bf16x8 v1 = *(const bf16x8*)(Vs + r64 + (((4 + quad) ^ s7) * 8));
        o[ch][jd] = __builtin_amdgcn_mfma_f32_16x16x32_bf16(v0, ap0, o[ch][jd], 0, 0, 0);
        o[ch][jd] = __builtin_amdgcn_mfma_f32_16x16x32_bf16(v1, ap1, o[ch][jd], 0, 0, 0);
      }
    }
  }

  for (int ch = 0; ch < 2; ++ch) {
    float s = lsum[ch];
    s += __shfl_xor(s, 16, 64);
    s += __shfl_xor(s, 32, 64);
    float inv = __builtin_amdgcn_rcpf(s);
    int q = qbase + ch * 16 + l15;
    __bf16* op = out + (size_t)(b * 512 + q) * 512 + h * 64;
    for (int jd = 0; jd < 4; ++jd) {
      bf16x4 pk;
      for (int r = 0; r < 4; ++r) pk[r] = (__bf16)(o[ch][jd][r] * inv);
      *(bf16x4*)(op + jd * 16 + quad * 4) = pk;
    }
  }
}

// ---------------------------------------------------------------- residual + layernorm
template <bool X1BF, bool WF, bool WB>
__global__ __launch_bounds__(256) void resid_ln(const float* __restrict__ X1f,
                                                const __bf16* __restrict__ X1b,
                                                const __bf16* __restrict__ X2,
                                                const float* __restrict__ bias,
                                                const float* __restrict__ g,
                                                const float* __restrict__ be,
                                                float* __restrict__ outf,
                                                __bf16* __restrict__ outb) {
  int row = blockIdx.x * 4 + (threadIdx.x >> 6);
  int lane = threadIdx.x & 63;
  float v[8];
  bf16x8 b8 = *(const bf16x8*)(X2 + (size_t)row * 512 + lane * 8);
  if (X1BF) {
    bf16x8 a = *(const bf16x8*)(X1b + (size_t)row * 512 + lane * 8);
    for (int i = 0; i < 8; ++i) v[i] = (float)a[i] + (float)b8[i];
  } else {
    const float4* r1 = (const float4*)(X1f + (size_t)row * 512);
    float4 a0 = r1[lane * 2], a1 = r1[lane * 2 + 1];
    v[0] = a0.x; v[1] = a0.y; v[2] = a0.z; v[3] = a0.w;
    v[4] = a1.x; v[5] = a1.y; v[6] = a1.z; v[7] = a1.w;
    for (int i = 0; i < 8; ++i) v[i] += (float)b8[i];
  }
  if (bias) {
    const float* bp = bias + lane * 8;
    for (int i = 0; i < 8; ++i) v[i] += bp[i];
  }
  float s = 0.f, sq = 0.f;
  for (int i = 0; i < 8; ++i) {
    s += v[i];
    sq += v[i] * v[i];
  }
  for (int m = 1; m < 64; m <<= 1) {
    s += __shfl_xor(s, m, 64);
    sq += __shfl_xor(sq, m, 64);
  }
  float mean = s * (1.f / 512.f);
  float var = sq * (1.f / 512.f) - mean * mean;
  float rstd = rsqrtf(var + LN_EPS);
  const float* gp = g + lane * 8;
  const float* bp2 = be + lane * 8;
  float o[8];
  for (int i = 0; i < 8; ++i) o[i] = (v[i] - mean) * rstd * gp[i] + bp2[i];
  if (WF) {
    float4 w0 = {o[0], o[1], o[2], o[3]}, w1 = {o[4], o[5], o[6], o[7]};
    ((float4*)(outf + (size_t)row * 512))[lane * 2] = w0;
    ((float4*)(outf + (size_t)row * 512))[lane * 2 + 1] = w1;
  }
  if (WB) {
    __bf16 tmp[8];
    for (int i = 0; i < 8; ++i) tmp[i] = (__bf16)o[i];
    *(bf16x8*)(outb + (size_t)row * 512 + lane * 8) = *(bf16x8*)tmp;
  }
}

// ---------------------------------------------------------------- launcher
extern "C" void kernel_launch(void* const* d_in, const int* in_sizes, int n_in,
                              void* d_out, int out_size, void* d_ws, size_t ws_size,
                              hipStream_t stream) {
  const float* x     = (const float*)d_in[0];
  const float* w_q   = (const float*)d_in[1];
  const float* w_k   = (const float*)d_in[2];
  const float* w_v   = (const float*)d_in[3];
  const float* w_o   = (const float*)d_in[4];
  const float* w_ff1 = (const float*)d_in[5];
  const float* b_ff1 = (const float*)d_in[6];
  const float* w_ff2 = (const float*)d_in[7];
  const float* b_ff2 = (const float*)d_in[8];
  const float* g1    = (const float*)d_in[9];
  const float* b1    = (const float*)d_in[10];
  const float* g2    = (const float*)d_in[11];
  const float* b2    = (const float*)d_in[12];
  float* out = (float*)d_out;

  char* ws = (char*)d_ws;
  size_t off = 0;
  auto alloc = [&](size_t bytes) -> void* {
    void* p = ws + off;
    off += (bytes + 255) & ~(size_t)255;
    return p;
  };
  __bf16* xb     = (__bf16*)alloc((size_t)Mrows * 512 * 2);
  __bf16* wt_qkv = (__bf16*)alloc((size_t)1536 * 512 * 2);
  __bf16* wt_o   = (__bf16*)alloc((size_t)512 * 512 * 2);
  __bf16* wt_ff1 = (__bf16*)alloc((size_t)2048 * 512 * 2);
  __bf16* wt_ff2 = (__bf16*)alloc((size_t)512 * 2048 * 2);
  __bf16* qkv    = (__bf16*)alloc((size_t)Mrows * 1536 * 2);
  float*  norms  = (float*)alloc((size_t)262144 * 4);
  __bf16* attn   = (__bf16*)alloc((size_t)Mrows * 512 * 2);
  __bf16* projb  = (__bf16*)alloc((size_t)Mrows * 512 * 2);
  __bf16* h1b    = (__bf16*)alloc((size_t)Mrows * 512 * 2);
  __bf16* mid    = (__bf16*)alloc((size_t)Mrows * 2048 * 2);
  __bf16* vtg    = mid;            // alias: dead before ff1 writes mid
  __bf16* f2o    = attn;           // alias: attn dead after w_o GEMM

  prep_kernel<<<8960, 256, 0, stream>>>(x, xb, w_q, w_k, w_v, w_o, w_ff1, w_ff2,
                                        wt_qkv, wt_qkv + 512 * 512, wt_qkv + 2 * 512 * 512,
                                        wt_o, wt_ff1, wt_ff2);

  // QKV (fused inverse norms + V-transpose into vtg)
  gemm_bt<4, 12, 1536, 512><<<dim3(12 * 128), 256, 0, stream>>>(xb, wt_qkv, qkv, nullptr,
                                                                norms, vtg);
  attn_kernel<<<dim3(1024), 256, 0, stream>>>(qkv, vtg, norms, attn);
  // w_o proj -> bf16
  gemm_bt<0, 4, 512, 512><<<dim3(4 * 128), 256, 0, stream>>>(attn, wt_o, projb, nullptr,
                                                             nullptr, nullptr);
  // LN1: x + projb -> h1b (bf16)
  resid_ln<false, false, true><<<4096, 256, 0, stream>>>(x, nullptr, projb, nullptr,
                                                         g1, b1, nullptr, h1b);
  // FFN1 (+bias, relu)
  gemm_bt<2, 16, 2048, 512><<<dim3(16 * 128), 256, 0, stream>>>(h1b, wt_ff1, mid, b_ff1,
                                                                nullptr, nullptr);
  // FFN2 -> bf16 (bias folded into LN2)
  gemm_bt<0, 4, 512, 2048><<<dim3(4 * 128), 256, 0, stream>>>(mid, wt_ff2, f2o, nullptr,
                                                              nullptr, nullptr);
  // LN2: h1b + f2o + b_ff2 -> out (f32)
  resid_ln<true, true, false><<<4096, 256, 0, stream>>>(nullptr, h1b, f2o, b_ff2,
                                                        g2, b2, out, nullptr);
}